// Round 5
// baseline (30900.461 us; speedup 1.0000x reference)
//
#include <hip/hip_runtime.h>
#include <math.h>

namespace {

constexpr int S = 128;   // seq
constexpr int B = 128;   // batch
constexpr int E = 256;   // embed
constexpr int H = 256;   // hidden

__device__ __forceinline__ float sigmoidf(float x) { return 1.0f / (1.0f + expf(-x)); }

// ---------------- init (fast path): h0 for 6 recurrences + zero barrier ----------------
__global__ void init_fast(const float* hQ, const float* hC, const float* hC2,
                          float* h0, int* bar) {
  int i = blockIdx.x * 256 + threadIdx.x;
  if (blockIdx.x == 0 && threadIdx.x < 256) bar[threadIdx.x] = 0;
  if (i >= 6 * B * H) return;
  int z = i / (B * H);
  int rem = i - z * (B * H);
  int input = z >> 1, dir = z & 1;
  const float* hs = input == 0 ? hQ : (input == 1 ? hC : hC2);
  h0[i] = hs[dir * B * H + rem];
}

// ---------------- input projection with fused embedding gather ----------------
// gi[z][t][b][u*4+g] = emb[tok[t,b]] @ Wih_dir^T + bih + bhh   (col-interleaved layout)
// grid (16 nblk, 128 mblk, 6 z), block 256, tile 128x64, acc 8x4, K=256.
__global__ __launch_bounds__(256, 3) void proj_gemm(
    const int* __restrict__ idxQ, const int* __restrict__ idxC, const int* __restrict__ idxC2,
    const float* __restrict__ emb,
    const float* __restrict__ Wih_f, const float* __restrict__ bih_f, const float* __restrict__ bhh_f,
    const float* __restrict__ Wih_b, const float* __restrict__ bih_b, const float* __restrict__ bhh_b,
    float* __restrict__ gi)
{
  const int z = blockIdx.z, input = z >> 1, dir = z & 1;
  const int n0 = blockIdx.x * 64;        // cols in interleaved space [0,1024)
  const int m0 = blockIdx.y * 128;       // rows m = t*B+b
  const int* idx = input == 0 ? idxQ : (input == 1 ? idxC : idxC2);
  const float* W  = dir ? Wih_b : Wih_f;
  const float* b1 = dir ? bih_b : bih_f;
  const float* b2 = dir ? bhh_b : bhh_f;

  __shared__ float Al[128][36];
  __shared__ float Bl[64][36];
  __shared__ int tok[128];
  const int tid = threadIdx.x;
  if (tid < 128) tok[tid] = idx[m0 + tid];
  const int tx = tid & 15, ty = tid >> 4;
  float acc[8][4] = {};

  for (int kb = 0; kb < E; kb += 32) {
    __syncthreads();
#pragma unroll
    for (int i = 0; i < 16; ++i) {
      int e = i * 256 + tid;
      int r = e >> 5, kk = e & 31;
      Al[r][kk] = emb[(long)tok[r] * E + kb + kk];
    }
#pragma unroll
    for (int i = 0; i < 8; ++i) {
      int e = i * 256 + tid;
      int c = e >> 5, kk = e & 31;
      int C = n0 + c;                         // interleaved col
      int gcol = (C & 3) * 256 + (C >> 2);    // W row
      Bl[c][kk] = W[(long)gcol * E + kb + kk];
    }
    __syncthreads();
#pragma unroll
    for (int k4 = 0; k4 < 8; ++k4) {
      float4 a[8], b[4];
#pragma unroll
      for (int i = 0; i < 8; ++i) a[i] = *(const float4*)&Al[ty + 16 * i][k4 * 4];
#pragma unroll
      for (int j = 0; j < 4; ++j) b[j] = *(const float4*)&Bl[tx + 16 * j][k4 * 4];
#pragma unroll
      for (int i = 0; i < 8; ++i)
#pragma unroll
        for (int j = 0; j < 4; ++j)
          acc[i][j] += a[i].x * b[j].x + a[i].y * b[j].y + a[i].z * b[j].z + a[i].w * b[j].w;
    }
  }
  float* gp = gi + (long)z * S * B * 1024;
#pragma unroll
  for (int i = 0; i < 8; ++i) {
    long m = m0 + ty + 16 * i;
#pragma unroll
    for (int j = 0; j < 4; ++j) {
      int C = n0 + tx + 16 * j;
      int gcol = (C & 3) * 256 + (C >> 2);
      gp[m * 1024 + C] = acc[i][j] + b1[gcol] + b2[gcol];
    }
  }
}

// ---------------- persistent cooperative LSTM: all 128 steps in one dispatch ----------
// 192 blocks = 6 z * 16 ublk(16 units) * 2 bblk(64 rows); 256 thr; Whh slice in LDS.
// Thread (tx=unit, rg): 4 rows x 4 gates. Per-z barrier between steps.
__global__ __launch_bounds__(256) void lstm_coop(
    const float* __restrict__ Whh_f, const float* __restrict__ Whh_b,
    const float* __restrict__ cQ, const float* __restrict__ cC, const float* __restrict__ cC2,
    const float* __restrict__ gi, float* __restrict__ hbuf0, float* __restrict__ hbuf1,
    float* __restrict__ out3, int* __restrict__ bar)
{
  const int bx = blockIdx.x;
  const int z = bx >> 5;
  const int r5 = bx & 31;
  const int u0 = (r5 >> 1) * 16;
  const int b0 = (r5 & 1) * 64;
  const int input = z >> 1, dir = z & 1;
  const int tid = threadIdx.x, tx = tid & 15, rg = tid >> 4;
  const int u = u0 + tx;
  const float* Whh = dir ? Whh_b : Whh_f;

  __shared__ float Wl[256][64];   // [k][uu*4+g] = Whh[g*256+u0+uu][k]  (64 KiB)

  {  // one-time W slice load (amortized over 128 steps)
    const int c = tid & 63, kq = tid >> 6;
    const int gcol = (c & 3) * 256 + u0 + (c >> 2);
    const float* src = Whh + (long)gcol * H + kq * 64;
#pragma unroll
    for (int i = 0; i < 64; i += 4) {
      float4 v = *(const float4*)(src + i);
      Wl[kq * 64 + i + 0][c] = v.x;
      Wl[kq * 64 + i + 1][c] = v.y;
      Wl[kq * 64 + i + 2][c] = v.z;
      Wl[kq * 64 + i + 3][c] = v.w;
    }
  }

  // cell state lives in registers for the whole sequence
  const float* cells = input == 0 ? cQ : (input == 1 ? cC : cC2);
  float creg[4];
#pragma unroll
  for (int ri = 0; ri < 4; ++ri)
    creg[ri] = cells[(long)dir * B * H + (long)(b0 + rg * 4 + ri) * H + u];

  __syncthreads();

  int* cnt = bar + z * 32;
  int* gen = bar + z * 32 + 16;
  float* op = out3 + (long)input * B * S * 2 * H;

  for (int t = 0; t < S; ++t) {
    const int t_eff = dir ? (S - 1 - t) : t;
    const float* hread = (t & 1) ? hbuf1 : hbuf0;
    float* hwrite = (t & 1) ? hbuf0 : hbuf1;

    // gi prefetch (consumed only in epilogue -> latency hidden under K-loop)
    float4 gv[4];
    const float* gp = gi + ((long)(z * S + t_eff) * B + b0) * 1024 + (long)u * 4;
#pragma unroll
    for (int ri = 0; ri < 4; ++ri)
      gv[ri] = *(const float4*)(gp + (long)(rg * 4 + ri) * 1024);

    float acc[4][4] = {};
    const float* hs = hread + ((long)z * B + b0) * H;
#pragma unroll 8
    for (int k4 = 0; k4 < 64; ++k4) {
      float4 w0 = *(const float4*)&Wl[k4 * 4 + 0][tx * 4];
      float4 w1 = *(const float4*)&Wl[k4 * 4 + 1][tx * 4];
      float4 w2 = *(const float4*)&Wl[k4 * 4 + 2][tx * 4];
      float4 w3 = *(const float4*)&Wl[k4 * 4 + 3][tx * 4];
#pragma unroll
      for (int ri = 0; ri < 4; ++ri) {
        float4 hv = *(const float4*)&hs[(rg * 4 + ri) * H + k4 * 4];
        acc[ri][0] += hv.x * w0.x + hv.y * w1.x + hv.z * w2.x + hv.w * w3.x;
        acc[ri][1] += hv.x * w0.y + hv.y * w1.y + hv.z * w2.y + hv.w * w3.y;
        acc[ri][2] += hv.x * w0.z + hv.y * w1.z + hv.z * w2.z + hv.w * w3.z;
        acc[ri][3] += hv.x * w0.w + hv.y * w1.w + hv.z * w2.w + hv.w * w3.w;
      }
    }

#pragma unroll
    for (int ri = 0; ri < 4; ++ri) {
      int b = b0 + rg * 4 + ri;
      float ig = sigmoidf(acc[ri][0] + gv[ri].x);
      float fg = sigmoidf(acc[ri][1] + gv[ri].y);
      float gg = tanhf(acc[ri][2] + gv[ri].z);
      float og = sigmoidf(acc[ri][3] + gv[ri].w);
      float cn = fg * creg[ri] + ig * gg;
      creg[ri] = cn;
      float hn = og * tanhf(cn);
      hwrite[((long)z * B + b) * H + u] = hn;
      op[((long)b * S + t_eff) * (2 * H) + dir * H + u] = hn;
    }

    // per-z grid barrier (32 blocks), sense = monotonically increasing gen
    __threadfence();
    __syncthreads();
    if (tid == 0) {
      int old = __hip_atomic_fetch_add(cnt, 1, __ATOMIC_ACQ_REL, __HIP_MEMORY_SCOPE_AGENT);
      if (old == 31) {
        __hip_atomic_store(cnt, 0, __ATOMIC_RELAXED, __HIP_MEMORY_SCOPE_AGENT);
        __hip_atomic_fetch_add(gen, 1, __ATOMIC_RELEASE, __HIP_MEMORY_SCOPE_AGENT);
      } else {
        while (__hip_atomic_load(gen, __ATOMIC_ACQUIRE, __HIP_MEMORY_SCOPE_AGENT) < t + 1) {
          __builtin_amdgcn_s_sleep(2);
        }
      }
    }
    __syncthreads();
    __threadfence();
  }
}

// ---------------- 128x64-tile fp32 GEMM, 8x4/thread, 3 blocks/CU ----------------
// NT: C = act(A@B^T [+bias]);  NN: C = A@B.  K%32==0, M%128==0, N%64==0.
// grid (N/64, M/128, batch), block 256.
template <bool NT, bool TANH, bool BIAS>
__global__ __launch_bounds__(256, 3) void gemm_f(
    const float* __restrict__ A, const float* __restrict__ Bm,
    const float* __restrict__ bias, float* __restrict__ C,
    int lda, int ldb, int ldc, int K, long sA, long sB, long sC)
{
  A += blockIdx.z * sA; Bm += blockIdx.z * sB; C += blockIdx.z * sC;
  const int n0 = blockIdx.x * 64, m0 = blockIdx.y * 128;
  __shared__ float Al[128][36];
  __shared__ float Bl[64][36];
  const int tid = threadIdx.x, tx = tid & 15, ty = tid >> 4;
  float acc[8][4] = {};
  for (int kb = 0; kb < K; kb += 32) {
    __syncthreads();
#pragma unroll
    for (int i = 0; i < 16; ++i) {
      int e = i * 256 + tid;
      int r = e >> 5, kk = e & 31;
      Al[r][kk] = A[(long)(m0 + r) * lda + kb + kk];
    }
    if (NT) {
#pragma unroll
      for (int i = 0; i < 8; ++i) {
        int e = i * 256 + tid;
        int c = e >> 5, kk = e & 31;
        Bl[c][kk] = Bm[(long)(n0 + c) * ldb + kb + kk];
      }
    } else {
#pragma unroll
      for (int i = 0; i < 8; ++i) {
        int e = i * 256 + tid;
        int c = e & 63, kk = e >> 6;
        Bl[c][kk] = Bm[(long)(kb + kk) * ldb + n0 + c];
      }
    }
    __syncthreads();
#pragma unroll
    for (int k4 = 0; k4 < 8; ++k4) {
      float4 a[8], b[4];
#pragma unroll
      for (int i = 0; i < 8; ++i) a[i] = *(const float4*)&Al[ty + 16 * i][k4 * 4];
#pragma unroll
      for (int j = 0; j < 4; ++j) b[j] = *(const float4*)&Bl[tx + 16 * j][k4 * 4];
#pragma unroll
      for (int i = 0; i < 8; ++i)
#pragma unroll
        for (int j = 0; j < 4; ++j)
          acc[i][j] += a[i].x * b[j].x + a[i].y * b[j].y + a[i].z * b[j].z + a[i].w * b[j].w;
    }
  }
#pragma unroll
  for (int i = 0; i < 8; ++i) {
    int m = m0 + ty + 16 * i;
#pragma unroll
    for (int j = 0; j < 4; ++j) {
      int n = n0 + tx + 16 * j;
      float v = acc[i][j];
      if (BIAS) v += bias[n];
      if (TANH) v = tanhf(v);
      C[(long)m * ldc + n] = v;
    }
  }
}

// ================== FALLBACK PATH (round-1, verified) ==================

__global__ void init_state(const float* hQ, const float* cQ,
                           const float* hC, const float* cC,
                           const float* hC2, const float* cC2,
                           float* h0, float* c0) {
  int i = blockIdx.x * 256 + threadIdx.x;
  if (i >= 6 * B * H) return;
  int z = i / (B * H);
  int rem = i - z * (B * H);
  int input = z >> 1, dir = z & 1;
  const float* hs = input == 0 ? hQ : (input == 1 ? hC : hC2);
  const float* cs = input == 0 ? cQ : (input == 1 ? cC : cC2);
  h0[i] = hs[dir * B * H + rem];
  c0[i] = cs[dir * B * H + rem];
}

__global__ __launch_bounds__(256) void lstm_step(
    const int* __restrict__ idxQ, const int* __restrict__ idxC, const int* __restrict__ idxC2,
    const float* __restrict__ emb,
    const float* __restrict__ Wih_f, const float* __restrict__ Whh_f,
    const float* __restrict__ bih_f, const float* __restrict__ bhh_f,
    const float* __restrict__ Wih_b, const float* __restrict__ Whh_b,
    const float* __restrict__ bih_b, const float* __restrict__ bhh_b,
    const float* __restrict__ hread, float* __restrict__ hwrite,
    float* __restrict__ cstate, float* __restrict__ out3, int t)
{
  const int z = blockIdx.z;
  const int input = z >> 1, dir = z & 1;
  const int u0 = blockIdx.x * 16;
  const int b0 = blockIdx.y * 64;
  const int t_eff = dir ? (S - 1 - t) : t;
  const int* idx = input == 0 ? idxQ : (input == 1 ? idxC : idxC2);
  const float* Wih = dir ? Wih_b : Wih_f;
  const float* Whh = dir ? Whh_b : Whh_f;
  const float* bih = dir ? bih_b : bih_f;
  const float* bhh = dir ? bhh_b : bhh_f;

  __shared__ float Al[64][68];
  __shared__ float Wl[64][68];
  __shared__ int tok[64];

  const int tid = threadIdx.x;
  if (tid < 64) tok[tid] = idx[t_eff * B + b0 + tid];

  const int uu = tid & 15;
  const int rg = tid >> 4;
  const int u = u0 + uu;

  float acc[4][4];
#pragma unroll
  for (int ri = 0; ri < 4; ++ri)
#pragma unroll
    for (int g = 0; g < 4; ++g)
      acc[ri][g] = bih[g * 256 + u] + bhh[g * 256 + u];

  for (int kc = 0; kc < 8; ++kc) {
    __syncthreads();
    if (kc < 4) {
      const int kb = kc * 64;
#pragma unroll
      for (int i = 0; i < 16; ++i) {
        int e = i * 256 + tid;
        int kk = e & 63, r = e >> 6;
        Al[r][kk] = emb[(long)tok[r] * E + kb + kk];
      }
    } else {
      const int kb = (kc - 4) * 64;
      const float* hs = hread + ((long)z * B + b0) * H + kb;
#pragma unroll
      for (int i = 0; i < 16; ++i) {
        int e = i * 256 + tid;
        int kk = e & 63, r = e >> 6;
        Al[r][kk] = hs[r * H + kk];
      }
    }
    {
      const float* Wsrc = (kc < 4) ? Wih : Whh;
      const int kb = (kc & 3) * 64;
#pragma unroll
      for (int i = 0; i < 16; ++i) {
        int e = i * 256 + tid;
        int kk = e & 63, c = e >> 6;
        int gcol = (c >> 4) * 256 + u0 + (c & 15);
        Wl[c][kk] = Wsrc[(long)gcol * H + kb + kk];
      }
    }
    __syncthreads();
#pragma unroll
    for (int k4 = 0; k4 < 64; k4 += 4) {
      float4 a[4], w[4];
#pragma unroll
      for (int ri = 0; ri < 4; ++ri) a[ri] = *(const float4*)&Al[rg * 4 + ri][k4];
#pragma unroll
      for (int g = 0; g < 4; ++g) w[g] = *(const float4*)&Wl[g * 16 + uu][k4];
#pragma unroll
      for (int ri = 0; ri < 4; ++ri)
#pragma unroll
        for (int g = 0; g < 4; ++g)
          acc[ri][g] += a[ri].x * w[g].x + a[ri].y * w[g].y
                      + a[ri].z * w[g].z + a[ri].w * w[g].w;
    }
  }

  float* cs = cstate + (long)z * B * H;
  float* hw = hwrite + (long)z * B * H;
  float* op = out3 + (long)input * B * S * 2 * H;
#pragma unroll
  for (int ri = 0; ri < 4; ++ri) {
    int b = b0 + rg * 4 + ri;
    float ig = sigmoidf(acc[ri][0]);
    float fg = sigmoidf(acc[ri][1]);
    float gg = tanhf(acc[ri][2]);
    float og = sigmoidf(acc[ri][3]);
    float cn = fg * cs[b * H + u] + ig * gg;
    float hn = og * tanhf(cn);
    cs[b * H + u] = cn;
    hw[b * H + u] = hn;
    op[((long)b * S + t_eff) * (2 * H) + dir * H + u] = hn;
  }
}

template <bool TANH>
__global__ __launch_bounds__(256) void gemm_nt(
    const float* __restrict__ A, const float* __restrict__ B_,
    const float* __restrict__ bias, float* __restrict__ C,
    int lda, int ldb, int ldc, int K, long sA, long sB, long sC)
{
  A += blockIdx.z * sA; B_ += blockIdx.z * sB; C += blockIdx.z * sC;
  const int n0 = blockIdx.x * 64, m0 = blockIdx.y * 64;
  __shared__ float Al[64][68], Bl[64][68];
  const int tid = threadIdx.x, uu = tid & 15, rg = tid >> 4;
  float acc[4][4] = {};
  for (int kb = 0; kb < K; kb += 64) {
    __syncthreads();
#pragma unroll
    for (int i = 0; i < 16; ++i) {
      int e = i * 256 + tid;
      int kk = e & 63, r = e >> 6;
      Al[r][kk] = A[(long)(m0 + r) * lda + kb + kk];
      Bl[r][kk] = B_[(long)(n0 + r) * ldb + kb + kk];
    }
    __syncthreads();
#pragma unroll
    for (int k4 = 0; k4 < 64; k4 += 4) {
      float4 a[4], w[4];
#pragma unroll
      for (int ri = 0; ri < 4; ++ri) a[ri] = *(const float4*)&Al[rg * 4 + ri][k4];
#pragma unroll
      for (int ci = 0; ci < 4; ++ci) w[ci] = *(const float4*)&Bl[ci * 16 + uu][k4];
#pragma unroll
      for (int ri = 0; ri < 4; ++ri)
#pragma unroll
        for (int ci = 0; ci < 4; ++ci)
          acc[ri][ci] += a[ri].x * w[ci].x + a[ri].y * w[ci].y
                       + a[ri].z * w[ci].z + a[ri].w * w[ci].w;
    }
  }
#pragma unroll
  for (int ri = 0; ri < 4; ++ri) {
    int m = m0 + rg * 4 + ri;
#pragma unroll
    for (int ci = 0; ci < 4; ++ci) {
      int n = n0 + ci * 16 + uu;
      float v = acc[ri][ci];
      if (bias) v += bias[n];
      if (TANH) v = tanhf(v);
      C[(long)m * ldc + n] = v;
    }
  }
}

__global__ __launch_bounds__(256) void gemm_nn(
    const float* __restrict__ A, const float* __restrict__ B_,
    float* __restrict__ C,
    int lda, int ldb, int ldc, int K, long sA, long sB, long sC)
{
  A += blockIdx.z * sA; B_ += blockIdx.z * sB; C += blockIdx.z * sC;
  const int n0 = blockIdx.x * 64, m0 = blockIdx.y * 64;
  __shared__ float Al[64][68];
  __shared__ float Bl[64][68];
  const int tid = threadIdx.x, uu = tid & 15, rg = tid >> 4;
  float acc[4][4] = {};
  for (int kb = 0; kb < K; kb += 64) {
    __syncthreads();
#pragma unroll
    for (int i = 0; i < 16; ++i) {
      int e = i * 256 + tid;
      int kk = e & 63, r = e >> 6;
      Al[r][kk] = A[(long)(m0 + r) * lda + kb + kk];
      Bl[r][kk] = B_[(long)(kb + r) * ldb + n0 + kk];
    }
    __syncthreads();
#pragma unroll
    for (int kk = 0; kk < 64; ++kk) {
      float4 w = *(const float4*)&Bl[kk][uu * 4];
      float a0 = Al[rg * 4 + 0][kk], a1 = Al[rg * 4 + 1][kk];
      float a2 = Al[rg * 4 + 2][kk], a3 = Al[rg * 4 + 3][kk];
      acc[0][0] += a0 * w.x; acc[0][1] += a0 * w.y; acc[0][2] += a0 * w.z; acc[0][3] += a0 * w.w;
      acc[1][0] += a1 * w.x; acc[1][1] += a1 * w.y; acc[1][2] += a1 * w.z; acc[1][3] += a1 * w.w;
      acc[2][0] += a2 * w.x; acc[2][1] += a2 * w.y; acc[2][2] += a2 * w.z; acc[2][3] += a2 * w.w;
      acc[3][0] += a3 * w.x; acc[3][1] += a3 * w.y; acc[3][2] += a3 * w.z; acc[3][3] += a3 * w.w;
    }
  }
#pragma unroll
  for (int ri = 0; ri < 4; ++ri) {
    int m = m0 + rg * 4 + ri;
    float4 v = make_float4(acc[ri][0], acc[ri][1], acc[ri][2], acc[ri][3]);
    *(float4*)&C[(long)m * ldc + n0 + uu * 4] = v;
  }
}

// ---------------- softmaxes ----------------
__global__ void softmax_row(const float* __restrict__ Hm, float* __restrict__ A) {
  const int row = blockIdx.x;
  const float* p = Hm + (long)row * S;
  const int l = threadIdx.x;
  float v0 = p[l], v1 = p[l + 64];
  float m = fmaxf(v0, v1);
#pragma unroll
  for (int o = 32; o > 0; o >>= 1) m = fmaxf(m, __shfl_xor(m, o));
  float e0 = expf(v0 - m), e1 = expf(v1 - m);
  float s = e0 + e1;
#pragma unroll
  for (int o = 32; o > 0; o >>= 1) s += __shfl_xor(s, o);
  float inv = 1.0f / s;
  float* q = A + (long)row * S;
  q[l] = e0 * inv; q[l + 64] = e1 * inv;
}

__global__ void softmax_colT(const float* __restrict__ Hm, float* __restrict__ A) {
  const int b = blockIdx.x >> 7;
  const int col = blockIdx.x & 127;
  const float* p = Hm + (long)b * S * S + col;
  const int l = threadIdx.x;
  float v0 = p[(long)l * S], v1 = p[(long)(l + 64) * S];
  float m = fmaxf(v0, v1);
#pragma unroll
  for (int o = 32; o > 0; o >>= 1) m = fmaxf(m, __shfl_xor(m, o));
  float e0 = expf(v0 - m), e1 = expf(v1 - m);
  float s = e0 + e1;
#pragma unroll
  for (int o = 32; o > 0; o >>= 1) s += __shfl_xor(s, o);
  float inv = 1.0f / s;
  float* q = A + ((long)b * S + col) * S;
  q[l] = e0 * inv; q[l + 64] = e1 * inv;
}

}  // namespace

extern "C" void kernel_launch(void* const* d_in, const int* in_sizes, int n_in,
                              void* d_out, int out_size, void* d_ws, size_t ws_size,
                              hipStream_t stream) {
  const int* idxQ    = (const int*)d_in[1];
  const int* idxC    = (const int*)d_in[2];
  const int* idxC2   = (const int*)d_in[3];
  const float* hQ    = (const float*)d_in[4];
  const float* cQ    = (const float*)d_in[5];
  const float* hC    = (const float*)d_in[6];
  const float* cC    = (const float*)d_in[7];
  const float* hC2   = (const float*)d_in[8];
  const float* cC2   = (const float*)d_in[9];
  const float* emb   = (const float*)d_in[10];
  const float* Wih_f = (const float*)d_in[11];
  const float* Whh_f = (const float*)d_in[12];
  const float* bih_f = (const float*)d_in[13];
  const float* bhh_f = (const float*)d_in[14];
  const float* Wih_b = (const float*)d_in[15];
  const float* Whh_b = (const float*)d_in[16];
  const float* bih_b = (const float*)d_in[17];
  const float* bhh_b = (const float*)d_in[18];
  const float* S1W   = (const float*)d_in[19];
  const float* S1b   = (const float*)d_in[20];
  float* out = (float*)d_out;

  const long OUT1 = (long)B * S * 2 * H;      // 8,388,608 floats
  const long ST   = (long)6 * B * H;          // 196,608 floats
  const long GI   = (long)6 * S * B * 1024;   // 100,663,296 floats

  const size_t need_fast = (size_t)(GI + 3 * OUT1 + 2 * ST + 256) * 4;  // ~505 MB

  if (ws_size >= need_fast) {
    // -------- fast path --------
    float* ws    = (float*)d_ws;
    float* gi    = ws;
    float* out3  = gi + GI;
    float* hbuf0 = out3 + 3 * OUT1;
    float* hbuf1 = hbuf0 + ST;
    int*   bar   = (int*)(hbuf1 + ST);
    // attention scratch aliases gi (dead after lstm_coop)
    float* Ct = ws;
    float* Hm = ws + OUT1;
    float* Ab = Hm + (long)B * S * S;

    init_fast<<<768, 256, 0, stream>>>(hQ, hC, hC2, hbuf0, bar);

    proj_gemm<<<dim3(16, 128, 6), 256, 0, stream>>>(
        idxQ, idxC, idxC2, emb, Wih_f, bih_f, bhh_f, Wih_b, bih_b, bhh_b, gi);

    {
      const float* a0 = Whh_f; const float* a1 = Whh_b;
      const float* a2 = cQ; const float* a3 = cC; const float* a4 = cC2;
      const float* a5 = gi; float* a6 = hbuf0; float* a7 = hbuf1;
      float* a8 = out3; int* a9 = bar;
      void* kargs[] = {(void*)&a0, (void*)&a1, (void*)&a2, (void*)&a3, (void*)&a4,
                       (void*)&a5, (void*)&a6, (void*)&a7, (void*)&a8, (void*)&a9};
      hipLaunchCooperativeKernel((const void*)lstm_coop, dim3(192), dim3(256),
                                 kargs, 0, stream);
    }

    for (int p = 0; p < 2; ++p) {
      const float* Q  = out3;
      const float* C0 = out3 + (long)(1 + p) * OUT1;
      // Ct = tanh(C0 @ S1W^T + S1b): M=16384, N=512, K=512
      gemm_f<true, true, true><<<dim3(8, 128, 1), 256, 0, stream>>>(
          C0, S1W, S1b, Ct, 512, 512, 512, 512, 0, 0, 0);
      // Hm[b] = Q[b] @ Ct[b]^T: per-batch M=N=128, K=512
      gemm_nt<false><<<dim3(2, 2, B), 256, 0, stream>>>(
          Q, Ct, nullptr, Hm, 512, 512, 128, 512,
          (long)S * 512, (long)S * 512, (long)S * S);
      softmax_row<<<B * S, 64, 0, stream>>>(Hm, Ab);
      // MQ[b] = AQ[b] @ Q[b]: M=128, N=512, K=128
      float* MQ = out + (long)(2 * p) * OUT1;
      gemm_f<false, false, false><<<dim3(8, 1, B), 256, 0, stream>>>(
          Ab, Q, nullptr, MQ, 128, 512, 512, 128,
          (long)S * S, (long)S * 512, (long)S * 512);
      softmax_colT<<<B * S, 64, 0, stream>>>(Hm, Ab);
      float* MC = out + (long)(2 * p + 1) * OUT1;
      gemm_f<false, false, false><<<dim3(8, 1, B), 256, 0, stream>>>(
          Ab, MQ, nullptr, MC, 128, 512, 512, 128,
          (long)S * S, (long)S * 512, (long)S * 512);
    }
    return;
  }

  // -------- fallback path: round-1 verified --------
  float* ws    = (float*)d_ws;
  float* out3  = ws;
  float* hbuf0 = out3 + 3 * OUT1;
  float* hbuf1 = hbuf0 + ST;
  float* cbuf  = hbuf1 + ST;
  float* Ct    = cbuf + ST;
  float* Hm    = Ct + OUT1;
  float* Ab    = Hm + (long)B * S * S;

  init_state<<<(6 * B * H + 255) / 256, 256, 0, stream>>>(hQ, cQ, hC, cC, hC2, cC2, hbuf0, cbuf);

  for (int t = 0; t < S; ++t) {
    float* hr = (t & 1) ? hbuf1 : hbuf0;
    float* hw = (t & 1) ? hbuf0 : hbuf1;
    lstm_step<<<dim3(16, 2, 6), 256, 0, stream>>>(
        idxQ, idxC, idxC2, emb,
        Wih_f, Whh_f, bih_f, bhh_f, Wih_b, Whh_b, bih_b, bhh_b,
        hr, hw, cbuf, out3, t);
  }

  for (int p = 0; p < 2; ++p) {
    const float* Q  = out3;
    const float* C0 = out3 + (long)(1 + p) * OUT1;
    gemm_nt<true><<<dim3(8, 256, 1), 256, 0, stream>>>(
        C0, S1W, S1b, Ct, 512, 512, 512, 512, 0, 0, 0);
    gemm_nt<false><<<dim3(2, 2, B), 256, 0, stream>>>(
        Q, Ct, nullptr, Hm, 512, 512, 128, 512,
        (long)S * 512, (long)S * 512, (long)S * S);
    softmax_row<<<B * S, 64, 0, stream>>>(Hm, Ab);
    float* MQ = out + (long)(2 * p) * OUT1;
    gemm_nn<<<dim3(8, 2, B), 256, 0, stream>>>(
        Ab, Q, MQ, 128, 512, 512, 128,
        (long)S * S, (long)S * 512, (long)S * 512);
    softmax_colT<<<B * S, 64, 0, stream>>>(Hm, Ab);
    float* MC = out + (long)(2 * p + 1) * OUT1;
    gemm_nn<<<dim3(8, 2, B), 256, 0, stream>>>(
        Ab, MQ, MC, 128, 512, 512, 128,
        (long)S * S, (long)S * 512, (long)S * 512);
  }
}

// Round 6
// 3230.222 us; speedup vs baseline: 9.5660x; 9.5660x over previous
//
#include <hip/hip_runtime.h>
#include <math.h>

namespace {

constexpr int S = 128;   // seq
constexpr int B = 128;   // batch
constexpr int E = 256;   // embed
constexpr int H = 256;   // hidden

typedef unsigned short u16;
typedef __attribute__((ext_vector_type(8))) short short8v;   // 8 bf16
typedef __attribute__((ext_vector_type(4))) float f32x4;

__device__ __forceinline__ float sigmoidf(float x) { return 1.0f / (1.0f + expf(-x)); }
__device__ __forceinline__ u16 bf16rnd(float x) {
  unsigned u = __float_as_uint(x);
  return (u16)((u + 0x7FFFu + ((u >> 16) & 1u)) >> 16);
}
__device__ __forceinline__ float bf2f(u16 v) { return __uint_as_float(((unsigned)v) << 16); }
__device__ __forceinline__ void split2(float x, u16& h, u16& l) {
  h = bf16rnd(x);
  l = bf16rnd(x - bf2f(h));
}
// gate-interleaved column mapping: col c in [0,1024) -> original W row
__device__ __forceinline__ int gcol_of(int c) {
  return ((c >> 4) & 3) * 256 + ((c & 15) + ((c >> 6) << 4));
}

// ================== split / prep kernels ==================

__global__ void split_pair(const float* __restrict__ src, u16* __restrict__ h,
                           u16* __restrict__ l, long n) {
  long i = (long)blockIdx.x * 256 + threadIdx.x;
  if (i < n) split2(src[i], h[i], l[i]);
}

__global__ void split_w_int(const float* __restrict__ W, u16* __restrict__ h,
                            u16* __restrict__ l) {
  int i = blockIdx.x * 256 + threadIdx.x;   // 1024*256
  int c = i >> 8, k = i & 255;
  split2(W[gcol_of(c) * 256 + k], h[i], l[i]);
}

__global__ void make_bint(const float* __restrict__ bih, const float* __restrict__ bhh,
                          float* __restrict__ bint) {
  int c = blockIdx.x * 256 + threadIdx.x;   // 1024
  int g = gcol_of(c);
  bint[c] = bih[g] + bhh[g];
}

__global__ void init_hc(const float* hQ, const float* cQ, const float* hC, const float* cC,
                        const float* hC2, const float* cC2,
                        u16* hH, u16* hL, float* cst) {
  int i = blockIdx.x * 256 + threadIdx.x;
  if (i >= 6 * B * H) return;
  int z = i / (B * H);
  int rem = i - z * (B * H);
  int input = z >> 1, dir = z & 1;
  const float* hs = input == 0 ? hQ : (input == 1 ? hC : hC2);
  const float* cs = input == 0 ? cQ : (input == 1 ? cC : cC2);
  split2(hs[dir * B * H + rem], hH[i], hL[i]);
  cst[i] = cs[dir * B * H + rem];
}

// ================== MFMA split-bf16 GEMM kernels ==================
// Common structure: 256 thr = 4 waves (2x2), block tile 128x128, wave tile 64x64
// = 4x4 MFMA 16x16x32 tiles, K staged in chunks of 32, LDS pitch 40 bf16.
// Fragment maps (gfx950 mfma_f32_16x16x32_bf16):
//   A: row = lane&15, k = (lane>>4)*8 + j    B: col = lane&15, same k
//   D: row = (lane>>4)*4 + reg, col = lane&15   [m89-verified]

#define MFMA_PROLOG                                        \
  const int tid = threadIdx.x;                             \
  const int wave = tid >> 6, lane = tid & 63;              \
  const int wr = wave >> 1, wc = wave & 1;                 \
  const int lrow = lane & 15, lk = lane >> 4;              \
  f32x4 acc[4][4];

#define MFMA_ZERO_ACC                                      \
  _Pragma("unroll") for (int a_ = 0; a_ < 4; ++a_)         \
  _Pragma("unroll") for (int b_ = 0; b_ < 4; ++b_)         \
      acc[a_][b_] = (f32x4){0.f, 0.f, 0.f, 0.f};

#define MFMA_INNER                                                             \
  __syncthreads();                                                             \
  short8v ah[4], al[4];                                                        \
  _Pragma("unroll") for (int mt = 0; mt < 4; ++mt) {                           \
    int r_ = wr * 64 + mt * 16 + lrow;                                         \
    ah[mt] = *(const short8v*)&Ah[r_ * 40 + lk * 8];                           \
    al[mt] = *(const short8v*)&Al[r_ * 40 + lk * 8];                           \
  }                                                                            \
  _Pragma("unroll") for (int nt = 0; nt < 4; ++nt) {                           \
    int c_ = wc * 64 + nt * 16 + lrow;                                         \
    short8v bh = *(const short8v*)&Bh[c_ * 40 + lk * 8];                       \
    short8v bl = *(const short8v*)&Bl[c_ * 40 + lk * 8];                       \
    _Pragma("unroll") for (int mt = 0; mt < 4; ++mt) {                         \
      acc[mt][nt] = __builtin_amdgcn_mfma_f32_16x16x32_bf16(ah[mt], bh, acc[mt][nt], 0, 0, 0); \
      acc[mt][nt] = __builtin_amdgcn_mfma_f32_16x16x32_bf16(ah[mt], bl, acc[mt][nt], 0, 0, 0); \
      acc[mt][nt] = __builtin_amdgcn_mfma_f32_16x16x32_bf16(al[mt], bh, acc[mt][nt], 0, 0, 0); \
    }                                                                          \
  }

// ---- input projection: giH/L[z][8192][1024] = emb_split @ WihI^T + bint ----
// phase selects which 64-t half of the sequence (per direction) is computed.
// grid (8, 64, 6), block 256.
__global__ __launch_bounds__(256) void proj_mfma(
    const int* __restrict__ idxQ, const int* __restrict__ idxC, const int* __restrict__ idxC2,
    const u16* __restrict__ embH, const u16* __restrict__ embL,
    const u16* __restrict__ wHf, const u16* __restrict__ wLf,
    const u16* __restrict__ wHb, const u16* __restrict__ wLb,
    const float* __restrict__ bintf, const float* __restrict__ bintb,
    u16* __restrict__ giH, u16* __restrict__ giL, int phase)
{
  const int z = blockIdx.z, input = z >> 1, dir = z & 1;
  const int n0 = blockIdx.x * 128, m0 = blockIdx.y * 128;
  const int tb = (dir == 0) ? phase * 64 : 64 - phase * 64;
  const int* idx = input == 0 ? idxQ : (input == 1 ? idxC : idxC2);
  const u16* wH = dir ? wHb : wHf;
  const u16* wL = dir ? wLb : wLf;
  const float* bint = dir ? bintb : bintf;

  __shared__ __align__(16) short Ah[128 * 40], Al[128 * 40], Bh[128 * 40], Bl[128 * 40];
  __shared__ int tok[128];
  MFMA_PROLOG
  if (tid < 128) tok[tid] = idx[tb * B + m0 + tid];
  MFMA_ZERO_ACC

  for (int kb = 0; kb < E; kb += 32) {
    __syncthreads();
#pragma unroll
    for (int i = 0; i < 2; ++i) {
      int e = i * 256 + tid;
      int r = e >> 2, kg = e & 3;
      long abase = (long)tok[r] * E + kb + kg * 8;
      *(short8v*)&Ah[r * 40 + kg * 8] = *(const short8v*)(embH + abase);
      *(short8v*)&Al[r * 40 + kg * 8] = *(const short8v*)(embL + abase);
      long bbase = (long)(n0 + r) * E + kb + kg * 8;
      *(short8v*)&Bh[r * 40 + kg * 8] = *(const short8v*)(wH + bbase);
      *(short8v*)&Bl[r * 40 + kg * 8] = *(const short8v*)(wL + bbase);
    }
    MFMA_INNER
  }

  u16* gh = giH + (long)z * 8192 * 1024;
  u16* gl = giL + (long)z * 8192 * 1024;
#pragma unroll
  for (int mt = 0; mt < 4; ++mt)
#pragma unroll
    for (int nt = 0; nt < 4; ++nt) {
      int c = n0 + wc * 64 + nt * 16 + lrow;
      float bv = bint[c];
#pragma unroll
      for (int rg = 0; rg < 4; ++rg) {
        long m = m0 + wr * 64 + mt * 16 + lk * 4 + rg;
        u16 hh, ll;
        split2(acc[mt][nt][rg] + bv, hh, ll);
        gh[m * 1024 + c] = hh;
        gl[m * 1024 + c] = ll;
      }
    }
}

// ---- recurrent step: g = gi[t] + h@WhhI^T, gates, h/c update ----
// grid (8, 6), block 256. M = 128 batches, N = 128 interleaved gate-cols, K = 256.
__global__ __launch_bounds__(256) void step_mfma(
    const u16* __restrict__ whHf, const u16* __restrict__ whLf,
    const u16* __restrict__ whHb, const u16* __restrict__ whLb,
    const u16* __restrict__ giH, const u16* __restrict__ giL,
    u16* __restrict__ hHbuf, u16* __restrict__ hLbuf,
    float* __restrict__ cst, u16* __restrict__ out3h, u16* __restrict__ out3l, int t)
{
  const int z = blockIdx.y, input = z >> 1, dir = z & 1;
  const int n0 = blockIdx.x * 128;
  const int t_eff = dir ? (S - 1 - t) : t;
  const int local = (dir == 0) ? (t & 63) : 63 - (t & 63);
  const u16* wH = dir ? whHb : whHf;
  const u16* wL = dir ? whLb : whLf;
  const long HS = (long)6 * B * H;
  const long zb = (long)z * B * H;
  const u16* hrH = hHbuf + (t & 1) * HS + zb;
  const u16* hrL = hLbuf + (t & 1) * HS + zb;

  __shared__ __align__(16) short Ah[128 * 40], Al[128 * 40], Bh[128 * 40], Bl[128 * 40];
  MFMA_PROLOG

  // acc init = gi (input projection + biases), fp32 from hi/lo
  {
    const u16* gh = giH + ((long)z * 64 + local) * B * 1024;
    const u16* gl = giL + ((long)z * 64 + local) * B * 1024;
#pragma unroll
    for (int mt = 0; mt < 4; ++mt)
#pragma unroll
      for (int nt = 0; nt < 4; ++nt) {
        int c = n0 + wc * 64 + nt * 16 + lrow;
#pragma unroll
        for (int rg = 0; rg < 4; ++rg) {
          long b = wr * 64 + mt * 16 + lk * 4 + rg;
          acc[mt][nt][rg] = bf2f(gh[b * 1024 + c]) + bf2f(gl[b * 1024 + c]);
        }
      }
  }

  for (int kb = 0; kb < H; kb += 32) {
    __syncthreads();
#pragma unroll
    for (int i = 0; i < 2; ++i) {
      int e = i * 256 + tid;
      int r = e >> 2, kg = e & 3;
      long abase = (long)r * H + kb + kg * 8;
      *(short8v*)&Ah[r * 40 + kg * 8] = *(const short8v*)(hrH + abase);
      *(short8v*)&Al[r * 40 + kg * 8] = *(const short8v*)(hrL + abase);
      long bbase = (long)(n0 + r) * H + kb + kg * 8;
      *(short8v*)&Bh[r * 40 + kg * 8] = *(const short8v*)(wH + bbase);
      *(short8v*)&Bl[r * 40 + kg * 8] = *(const short8v*)(wL + bbase);
    }
    MFMA_INNER
  }

  float* cz = cst + zb;
  u16* hwH = hHbuf + ((t & 1) ^ 1) * HS + zb;
  u16* hwL = hLbuf + ((t & 1) ^ 1) * HS + zb;
  u16* o3h = out3h + (long)input * B * S * 512;
  u16* o3l = out3l + (long)input * B * S * 512;
  const int u = ((n0 >> 6) + wc) * 16 + lrow;   // unit; gate == nt
#pragma unroll
  for (int mt = 0; mt < 4; ++mt)
#pragma unroll
    for (int rg = 0; rg < 4; ++rg) {
      int b = wr * 64 + mt * 16 + lk * 4 + rg;
      float ig = sigmoidf(acc[mt][0][rg]);
      float fg = sigmoidf(acc[mt][1][rg]);
      float gg = tanhf(acc[mt][2][rg]);
      float og = sigmoidf(acc[mt][3][rg]);
      float cn = fg * cz[b * H + u] + ig * gg;
      cz[b * H + u] = cn;
      float hn = og * tanhf(cn);
      u16 hh, hl;
      split2(hn, hh, hl);
      hwH[b * H + u] = hh;
      hwL[b * H + u] = hl;
      long oi = ((long)b * S + t_eff) * 512 + dir * 256 + u;
      o3h[oi] = hh;
      o3l[oi] = hl;
    }
}

// ---- Ct = tanh(C0 @ S1W^T + S1b), output split hi/lo ----
// grid (4, 128), block 256. M=16384, N=512, K=512.
__global__ __launch_bounds__(256) void ct_mfma(
    const u16* __restrict__ aH, const u16* __restrict__ aL,
    const u16* __restrict__ s1H, const u16* __restrict__ s1L,
    const float* __restrict__ s1b,
    u16* __restrict__ ctH, u16* __restrict__ ctL)
{
  const int n0 = blockIdx.x * 128, m0 = blockIdx.y * 128;
  __shared__ __align__(16) short Ah[128 * 40], Al[128 * 40], Bh[128 * 40], Bl[128 * 40];
  MFMA_PROLOG
  MFMA_ZERO_ACC

  for (int kb = 0; kb < 512; kb += 32) {
    __syncthreads();
#pragma unroll
    for (int i = 0; i < 2; ++i) {
      int e = i * 256 + tid;
      int r = e >> 2, kg = e & 3;
      long abase = (long)(m0 + r) * 512 + kb + kg * 8;
      *(short8v*)&Ah[r * 40 + kg * 8] = *(const short8v*)(aH + abase);
      *(short8v*)&Al[r * 40 + kg * 8] = *(const short8v*)(aL + abase);
      long bbase = (long)(n0 + r) * 512 + kb + kg * 8;
      *(short8v*)&Bh[r * 40 + kg * 8] = *(const short8v*)(s1H + bbase);
      *(short8v*)&Bl[r * 40 + kg * 8] = *(const short8v*)(s1L + bbase);
    }
    MFMA_INNER
  }

#pragma unroll
  for (int mt = 0; mt < 4; ++mt)
#pragma unroll
    for (int nt = 0; nt < 4; ++nt) {
      int c = n0 + wc * 64 + nt * 16 + lrow;
      float bv = s1b[c];
#pragma unroll
      for (int rg = 0; rg < 4; ++rg) {
        long m = m0 + wr * 64 + mt * 16 + lk * 4 + rg;
        u16 hh, ll;
        split2(tanhf(acc[mt][nt][rg] + bv), hh, ll);
        ctH[m * 512 + c] = hh;
        ctL[m * 512 + c] = ll;
      }
    }
}

// ---- Hm[b] = Q[b] @ Ct[b]^T (fp32 out) ----
// grid (128), block 256. M=N=128, K=512 per batch.
__global__ __launch_bounds__(256) void hm_mfma(
    const u16* __restrict__ qH, const u16* __restrict__ qL,
    const u16* __restrict__ ctH, const u16* __restrict__ ctL,
    float* __restrict__ Hm)
{
  const int bb = blockIdx.x;
  const u16* aH = qH + (long)bb * S * 512;
  const u16* aL = qL + (long)bb * S * 512;
  const u16* bH = ctH + (long)bb * S * 512;
  const u16* bL = ctL + (long)bb * S * 512;
  __shared__ __align__(16) short Ah[128 * 40], Al[128 * 40], Bh[128 * 40], Bl[128 * 40];
  MFMA_PROLOG
  MFMA_ZERO_ACC

  for (int kb = 0; kb < 512; kb += 32) {
    __syncthreads();
#pragma unroll
    for (int i = 0; i < 2; ++i) {
      int e = i * 256 + tid;
      int r = e >> 2, kg = e & 3;
      long base = (long)r * 512 + kb + kg * 8;
      *(short8v*)&Ah[r * 40 + kg * 8] = *(const short8v*)(aH + base);
      *(short8v*)&Al[r * 40 + kg * 8] = *(const short8v*)(aL + base);
      *(short8v*)&Bh[r * 40 + kg * 8] = *(const short8v*)(bH + base);
      *(short8v*)&Bl[r * 40 + kg * 8] = *(const short8v*)(bL + base);
    }
    MFMA_INNER
  }

  float* out = Hm + (long)bb * S * S;
#pragma unroll
  for (int mt = 0; mt < 4; ++mt)
#pragma unroll
    for (int nt = 0; nt < 4; ++nt) {
      int c = wc * 64 + nt * 16 + lrow;
#pragma unroll
      for (int rg = 0; rg < 4; ++rg) {
        int m = wr * 64 + mt * 16 + lk * 4 + rg;
        out[(long)m * S + c] = acc[mt][nt][rg];
      }
    }
}

// ================== fp32 helper GEMMs (verified R1 lineage) ==================

// C = A @ B, B given as bf16 hi/lo planes (reconstructed fp32).
__global__ __launch_bounds__(256) void gemm_nn_hl(
    const float* __restrict__ A, const u16* __restrict__ bHp, const u16* __restrict__ bLp,
    float* __restrict__ C, int lda, int ldb, int ldc, int K, long sA, long sB, long sC)
{
  A += blockIdx.z * sA; bHp += blockIdx.z * sB; bLp += blockIdx.z * sB; C += blockIdx.z * sC;
  const int n0 = blockIdx.x * 64, m0 = blockIdx.y * 64;
  __shared__ float Alds[64][68];
  __shared__ float Blds[64][68];
  const int tid = threadIdx.x, uu = tid & 15, rg = tid >> 4;
  float acc[4][4] = {};
  for (int kb = 0; kb < K; kb += 64) {
    __syncthreads();
#pragma unroll
    for (int i = 0; i < 16; ++i) {
      int e = i * 256 + tid;
      int kk = e & 63, r = e >> 6;
      Alds[r][kk] = A[(long)(m0 + r) * lda + kb + kk];
      long bi = (long)(kb + r) * ldb + n0 + kk;
      Blds[r][kk] = bf2f(bHp[bi]) + bf2f(bLp[bi]);
    }
    __syncthreads();
#pragma unroll
    for (int kk = 0; kk < 64; ++kk) {
      float4 w = *(const float4*)&Blds[kk][uu * 4];
      float a0 = Alds[rg * 4 + 0][kk], a1 = Alds[rg * 4 + 1][kk];
      float a2 = Alds[rg * 4 + 2][kk], a3 = Alds[rg * 4 + 3][kk];
      acc[0][0] += a0 * w.x; acc[0][1] += a0 * w.y; acc[0][2] += a0 * w.z; acc[0][3] += a0 * w.w;
      acc[1][0] += a1 * w.x; acc[1][1] += a1 * w.y; acc[1][2] += a1 * w.z; acc[1][3] += a1 * w.w;
      acc[2][0] += a2 * w.x; acc[2][1] += a2 * w.y; acc[2][2] += a2 * w.z; acc[2][3] += a2 * w.w;
      acc[3][0] += a3 * w.x; acc[3][1] += a3 * w.y; acc[3][2] += a3 * w.z; acc[3][3] += a3 * w.w;
    }
  }
#pragma unroll
  for (int ri = 0; ri < 4; ++ri) {
    int m = m0 + rg * 4 + ri;
    float4 v = make_float4(acc[ri][0], acc[ri][1], acc[ri][2], acc[ri][3]);
    *(float4*)&C[(long)m * ldc + n0 + uu * 4] = v;
  }
}

__global__ __launch_bounds__(256) void gemm_nn(
    const float* __restrict__ A, const float* __restrict__ B_,
    float* __restrict__ C,
    int lda, int ldb, int ldc, int K, long sA, long sB, long sC)
{
  A += blockIdx.z * sA; B_ += blockIdx.z * sB; C += blockIdx.z * sC;
  const int n0 = blockIdx.x * 64, m0 = blockIdx.y * 64;
  __shared__ float Alds[64][68];
  __shared__ float Blds[64][68];
  const int tid = threadIdx.x, uu = tid & 15, rg = tid >> 4;
  float acc[4][4] = {};
  for (int kb = 0; kb < K; kb += 64) {
    __syncthreads();
#pragma unroll
    for (int i = 0; i < 16; ++i) {
      int e = i * 256 + tid;
      int kk = e & 63, r = e >> 6;
      Alds[r][kk] = A[(long)(m0 + r) * lda + kb + kk];
      Blds[r][kk] = B_[(long)(kb + r) * ldb + n0 + kk];
    }
    __syncthreads();
#pragma unroll
    for (int kk = 0; kk < 64; ++kk) {
      float4 w = *(const float4*)&Blds[kk][uu * 4];
      float a0 = Alds[rg * 4 + 0][kk], a1 = Alds[rg * 4 + 1][kk];
      float a2 = Alds[rg * 4 + 2][kk], a3 = Alds[rg * 4 + 3][kk];
      acc[0][0] += a0 * w.x; acc[0][1] += a0 * w.y; acc[0][2] += a0 * w.z; acc[0][3] += a0 * w.w;
      acc[1][0] += a1 * w.x; acc[1][1] += a1 * w.y; acc[1][2] += a1 * w.z; acc[1][3] += a1 * w.w;
      acc[2][0] += a2 * w.x; acc[2][1] += a2 * w.y; acc[2][2] += a2 * w.z; acc[2][3] += a2 * w.w;
      acc[3][0] += a3 * w.x; acc[3][1] += a3 * w.y; acc[3][2] += a3 * w.z; acc[3][3] += a3 * w.w;
    }
  }
#pragma unroll
  for (int ri = 0; ri < 4; ++ri) {
    int m = m0 + rg * 4 + ri;
    float4 v = make_float4(acc[ri][0], acc[ri][1], acc[ri][2], acc[ri][3]);
    *(float4*)&C[(long)m * ldc + n0 + uu * 4] = v;
  }
}

// ---------------- softmaxes ----------------
__global__ void softmax_row(const float* __restrict__ Hm, float* __restrict__ A) {
  const int row = blockIdx.x;
  const float* p = Hm + (long)row * S;
  const int l = threadIdx.x;
  float v0 = p[l], v1 = p[l + 64];
  float m = fmaxf(v0, v1);
#pragma unroll
  for (int o = 32; o > 0; o >>= 1) m = fmaxf(m, __shfl_xor(m, o));
  float e0 = expf(v0 - m), e1 = expf(v1 - m);
  float s = e0 + e1;
#pragma unroll
  for (int o = 32; o > 0; o >>= 1) s += __shfl_xor(s, o);
  float inv = 1.0f / s;
  float* q = A + (long)row * S;
  q[l] = e0 * inv; q[l + 64] = e1 * inv;
}

__global__ void softmax_colT(const float* __restrict__ Hm, float* __restrict__ A) {
  const int b = blockIdx.x >> 7;
  const int col = blockIdx.x & 127;
  const float* p = Hm + (long)b * S * S + col;
  const int l = threadIdx.x;
  float v0 = p[(long)l * S], v1 = p[(long)(l + 64) * S];
  float m = fmaxf(v0, v1);
#pragma unroll
  for (int o = 32; o > 0; o >>= 1) m = fmaxf(m, __shfl_xor(m, o));
  float e0 = expf(v0 - m), e1 = expf(v1 - m);
  float s = e0 + e1;
#pragma unroll
  for (int o = 32; o > 0; o >>= 1) s += __shfl_xor(s, o);
  float inv = 1.0f / s;
  float* q = A + ((long)b * S + col) * S;
  q[l] = e0 * inv; q[l + 64] = e1 * inv;
}

// ================== FALLBACK PATH (round-1, verified) ==================

__global__ void init_state(const float* hQ, const float* cQ,
                           const float* hC, const float* cC,
                           const float* hC2, const float* cC2,
                           float* h0, float* c0) {
  int i = blockIdx.x * 256 + threadIdx.x;
  if (i >= 6 * B * H) return;
  int z = i / (B * H);
  int rem = i - z * (B * H);
  int input = z >> 1, dir = z & 1;
  const float* hs = input == 0 ? hQ : (input == 1 ? hC : hC2);
  const float* cs = input == 0 ? cQ : (input == 1 ? cC : cC2);
  h0[i] = hs[dir * B * H + rem];
  c0[i] = cs[dir * B * H + rem];
}

__global__ __launch_bounds__(256) void lstm_step(
    const int* __restrict__ idxQ, const int* __restrict__ idxC, const int* __restrict__ idxC2,
    const float* __restrict__ emb,
    const float* __restrict__ Wih_f, const float* __restrict__ Whh_f,
    const float* __restrict__ bih_f, const float* __restrict__ bhh_f,
    const float* __restrict__ Wih_b, const float* __restrict__ Whh_b,
    const float* __restrict__ bih_b, const float* __restrict__ bhh_b,
    const float* __restrict__ hread, float* __restrict__ hwrite,
    float* __restrict__ cstate, float* __restrict__ out3, int t)
{
  const int z = blockIdx.z;
  const int input = z >> 1, dir = z & 1;
  const int u0 = blockIdx.x * 16;
  const int b0 = blockIdx.y * 64;
  const int t_eff = dir ? (S - 1 - t) : t;
  const int* idx = input == 0 ? idxQ : (input == 1 ? idxC : idxC2);
  const float* Wih = dir ? Wih_b : Wih_f;
  const float* Whh = dir ? Whh_b : Whh_f;
  const float* bih = dir ? bih_b : bih_f;
  const float* bhh = dir ? bhh_b : bhh_f;

  __shared__ float Alds[64][68];
  __shared__ float Wl[64][68];
  __shared__ int tok[64];

  const int tid = threadIdx.x;
  if (tid < 64) tok[tid] = idx[t_eff * B + b0 + tid];

  const int uu = tid & 15;
  const int rg = tid >> 4;
  const int u = u0 + uu;

  float acc[4][4];
#pragma unroll
  for (int ri = 0; ri < 4; ++ri)
#pragma unroll
    for (int g = 0; g < 4; ++g)
      acc[ri][g] = bih[g * 256 + u] + bhh[g * 256 + u];

  for (int kc = 0; kc < 8; ++kc) {
    __syncthreads();
    if (kc < 4) {
      const int kb = kc * 64;
#pragma unroll
      for (int i = 0; i < 16; ++i) {
        int e = i * 256 + tid;
        int kk = e & 63, r = e >> 6;
        Alds[r][kk] = emb[(long)tok[r] * E + kb + kk];
      }
    } else {
      const int kb = (kc - 4) * 64;
      const float* hs = hread + ((long)z * B + b0) * H + kb;
#pragma unroll
      for (int i = 0; i < 16; ++i) {
        int e = i * 256 + tid;
        int kk = e & 63, r = e >> 6;
        Alds[r][kk] = hs[r * H + kk];
      }
    }
    {
      const float* Wsrc = (kc < 4) ? Wih : Whh;
      const int kb = (kc & 3) * 64;
#pragma unroll
      for (int i = 0; i < 16; ++i) {
        int e = i * 256 + tid;
        int kk = e & 63, c = e >> 6;
        int gcol = (c >> 4) * 256 + u0 + (c & 15);
        Wl[c][kk] = Wsrc[(long)gcol * H + kb + kk];
      }
    }
    __syncthreads();
#pragma unroll
    for (int k4 = 0; k4 < 64; k4 += 4) {
      float4 a[4], w[4];
#pragma unroll
      for (int ri = 0; ri < 4; ++ri) a[ri] = *(const float4*)&Alds[rg * 4 + ri][k4];
#pragma unroll
      for (int g = 0; g < 4; ++g) w[g] = *(const float4*)&Wl[g * 16 + uu][k4];
#pragma unroll
      for (int ri = 0; ri < 4; ++ri)
#pragma unroll
        for (int g = 0; g < 4; ++g)
          acc[ri][g] += a[ri].x * w[g].x + a[ri].y * w[g].y
                      + a[ri].z * w[g].z + a[ri].w * w[g].w;
    }
  }

  float* cs = cstate + (long)z * B * H;
  float* hw = hwrite + (long)z * B * H;
  float* op = out3 + (long)input * B * S * 2 * H;
#pragma unroll
  for (int ri = 0; ri < 4; ++ri) {
    int b = b0 + rg * 4 + ri;
    float ig = sigmoidf(acc[ri][0]);
    float fg = sigmoidf(acc[ri][1]);
    float gg = tanhf(acc[ri][2]);
    float og = sigmoidf(acc[ri][3]);
    float cn = fg * cs[b * H + u] + ig * gg;
    float hn = og * tanhf(cn);
    cs[b * H + u] = cn;
    hw[b * H + u] = hn;
    op[((long)b * S + t_eff) * (2 * H) + dir * H + u] = hn;
  }
}

template <bool TANH>
__global__ __launch_bounds__(256) void gemm_nt(
    const float* __restrict__ A, const float* __restrict__ B_,
    const float* __restrict__ bias, float* __restrict__ C,
    int lda, int ldb, int ldc, int K, long sA, long sB, long sC)
{
  A += blockIdx.z * sA; B_ += blockIdx.z * sB; C += blockIdx.z * sC;
  const int n0 = blockIdx.x * 64, m0 = blockIdx.y * 64;
  __shared__ float Alds[64][68], Blds[64][68];
  const int tid = threadIdx.x, uu = tid & 15, rg = tid >> 4;
  float acc[4][4] = {};
  for (int kb = 0; kb < K; kb += 64) {
    __syncthreads();
#pragma unroll
    for (int i = 0; i < 16; ++i) {
      int e = i * 256 + tid;
      int kk = e & 63, r = e >> 6;
      Alds[r][kk] = A[(long)(m0 + r) * lda + kb + kk];
      Blds[r][kk] = B_[(long)(n0 + r) * ldb + kb + kk];
    }
    __syncthreads();
#pragma unroll
    for (int k4 = 0; k4 < 64; k4 += 4) {
      float4 a[4], w[4];
#pragma unroll
      for (int ri = 0; ri < 4; ++ri) a[ri] = *(const float4*)&Alds[rg * 4 + ri][k4];
#pragma unroll
      for (int ci = 0; ci < 4; ++ci) w[ci] = *(const float4*)&Blds[ci * 16 + uu][k4];
#pragma unroll
      for (int ri = 0; ri < 4; ++ri)
#pragma unroll
        for (int ci = 0; ci < 4; ++ci)
          acc[ri][ci] += a[ri].x * w[ci].x + a[ri].y * w[ci].y
                       + a[ri].z * w[ci].z + a[ri].w * w[ci].w;
    }
  }
#pragma unroll
  for (int ri = 0; ri < 4; ++ri) {
    int m = m0 + rg * 4 + ri;
#pragma unroll
    for (int ci = 0; ci < 4; ++ci) {
      int n = n0 + ci * 16 + uu;
      float v = acc[ri][ci];
      if (bias) v += bias[n];
      if (TANH) v = tanhf(v);
      C[(long)m * ldc + n] = v;
    }
  }
}

}  // namespace

extern "C" void kernel_launch(void* const* d_in, const int* in_sizes, int n_in,
                              void* d_out, int out_size, void* d_ws, size_t ws_size,
                              hipStream_t stream) {
  const int* idxQ    = (const int*)d_in[1];
  const int* idxC    = (const int*)d_in[2];
  const int* idxC2   = (const int*)d_in[3];
  const float* hQ    = (const float*)d_in[4];
  const float* cQ    = (const float*)d_in[5];
  const float* hC    = (const float*)d_in[6];
  const float* cC    = (const float*)d_in[7];
  const float* hC2   = (const float*)d_in[8];
  const float* cC2   = (const float*)d_in[9];
  const float* emb   = (const float*)d_in[10];
  const float* Wih_f = (const float*)d_in[11];
  const float* Whh_f = (const float*)d_in[12];
  const float* bih_f = (const float*)d_in[13];
  const float* bhh_f = (const float*)d_in[14];
  const float* Wih_b = (const float*)d_in[15];
  const float* Whh_b = (const float*)d_in[16];
  const float* bih_b = (const float*)d_in[17];
  const float* bhh_b = (const float*)d_in[18];
  const float* S1W   = (const float*)d_in[19];
  const float* S1b   = (const float*)d_in[20];
  float* out = (float*)d_out;

  const long V = 50000;
  const long OUT1 = (long)B * S * 2 * H;   // 8,388,608 floats per input

  // -------- fast-path workspace layout (bytes) --------
  size_t off = 0;
  auto alloc = [&](size_t bytes) { size_t o = off; off += (bytes + 255) & ~(size_t)255; return o; };
  const size_t o_giH  = alloc((size_t)6 * 8192 * 1024 * 2);
  const size_t o_giL  = alloc((size_t)6 * 8192 * 1024 * 2);
  const size_t o_o3h  = alloc((size_t)3 * B * S * 512 * 2);
  const size_t o_o3l  = alloc((size_t)3 * B * S * 512 * 2);
  const size_t o_embH = alloc((size_t)V * E * 2);
  const size_t o_embL = alloc((size_t)V * E * 2);
  const size_t o_wihHf = alloc(1024 * 256 * 2), o_wihLf = alloc(1024 * 256 * 2);
  const size_t o_wihHb = alloc(1024 * 256 * 2), o_wihLb = alloc(1024 * 256 * 2);
  const size_t o_whhHf = alloc(1024 * 256 * 2), o_whhLf = alloc(1024 * 256 * 2);
  const size_t o_whhHb = alloc(1024 * 256 * 2), o_whhLb = alloc(1024 * 256 * 2);
  const size_t o_s1H  = alloc(512 * 512 * 2), o_s1L = alloc(512 * 512 * 2);
  const size_t o_bintf = alloc(1024 * 4), o_bintb = alloc(1024 * 4);
  const size_t o_hH   = alloc((size_t)2 * 6 * B * H * 2);
  const size_t o_hL   = alloc((size_t)2 * 6 * B * H * 2);
  const size_t o_cst  = alloc((size_t)6 * B * H * 4);
  const size_t need_fast = off;

  if (ws_size >= need_fast) {
    char* base = (char*)d_ws;
    u16* giH = (u16*)(base + o_giH);
    u16* giL = (u16*)(base + o_giL);
    u16* o3h = (u16*)(base + o_o3h);
    u16* o3l = (u16*)(base + o_o3l);
    u16* embH = (u16*)(base + o_embH);
    u16* embL = (u16*)(base + o_embL);
    u16* wihHf = (u16*)(base + o_wihHf); u16* wihLf = (u16*)(base + o_wihLf);
    u16* wihHb = (u16*)(base + o_wihHb); u16* wihLb = (u16*)(base + o_wihLb);
    u16* whhHf = (u16*)(base + o_whhHf); u16* whhLf = (u16*)(base + o_whhLf);
    u16* whhHb = (u16*)(base + o_whhHb); u16* whhLb = (u16*)(base + o_whhLb);
    u16* s1H = (u16*)(base + o_s1H); u16* s1L = (u16*)(base + o_s1L);
    float* bintf = (float*)(base + o_bintf);
    float* bintb = (float*)(base + o_bintb);
    u16* hH = (u16*)(base + o_hH);
    u16* hL = (u16*)(base + o_hL);
    float* cst = (float*)(base + o_cst);
    // attention scratch aliases gi (dead after last step_mfma)
    u16* ctH = (u16*)(base + o_giH);
    u16* ctL = ctH + (size_t)B * S * 512;
    float* Hm = (float*)(ctL + (size_t)B * S * 512);
    float* Ab = Hm + (size_t)B * S * S;

    // ---- prep: splits ----
    split_pair<<<(int)((V * E + 255) / 256), 256, 0, stream>>>(emb, embH, embL, V * E);
    split_w_int<<<1024, 256, 0, stream>>>(Wih_f, wihHf, wihLf);
    split_w_int<<<1024, 256, 0, stream>>>(Wih_b, wihHb, wihLb);
    split_w_int<<<1024, 256, 0, stream>>>(Whh_f, whhHf, whhLf);
    split_w_int<<<1024, 256, 0, stream>>>(Whh_b, whhHb, whhLb);
    split_pair<<<1024, 256, 0, stream>>>(S1W, s1H, s1L, 512 * 512);
    make_bint<<<4, 256, 0, stream>>>(bih_f, bhh_f, bintf);
    make_bint<<<4, 256, 0, stream>>>(bih_b, bhh_b, bintb);
    init_hc<<<(6 * B * H + 255) / 256, 256, 0, stream>>>(hQ, cQ, hC, cC, hC2, cC2, hH, hL, cst);

    // ---- LSTM: two phases (gi buffer covers 64 timesteps per direction) ----
    for (int phase = 0; phase < 2; ++phase) {
      proj_mfma<<<dim3(8, 64, 6), 256, 0, stream>>>(
          idxQ, idxC, idxC2, embH, embL,
          wihHf, wihLf, wihHb, wihLb, bintf, bintb, giH, giL, phase);
      for (int t = phase * 64; t < phase * 64 + 64; ++t) {
        step_mfma<<<dim3(8, 6), 256, 0, stream>>>(
            whhHf, whhLf, whhHb, whhLb, giH, giL, hH, hL, cst, o3h, o3l, t);
      }
    }

    // ---- attention x2 ----
    for (int p = 0; p < 2; ++p) {
      const u16* aH = o3h + (size_t)(1 + p) * B * S * 512;
      const u16* aL = o3l + (size_t)(1 + p) * B * S * 512;
      ct_mfma<<<dim3(4, 128), 256, 0, stream>>>(aH, aL, s1H, s1L, S1b, ctH, ctL);
      hm_mfma<<<128, 256, 0, stream>>>(o3h, o3l, ctH, ctL, Hm);
      softmax_row<<<B * S, 64, 0, stream>>>(Hm, Ab);
      float* MQ = out + (long)(2 * p) * OUT1;
      gemm_nn_hl<<<dim3(8, 2, B), 256, 0, stream>>>(
          Ab, o3h, o3l, MQ, 128, 512, 512, 128,
          (long)S * S, (long)S * 512, (long)S * 512);
      softmax_colT<<<B * S, 64, 0, stream>>>(Hm, Ab);
      float* MC = out + (long)(2 * p + 1) * OUT1;
      gemm_nn<<<dim3(8, 2, B), 256, 0, stream>>>(
          Ab, MQ, MC, 128, 512, 512, 128,
          (long)S * S, (long)S * 512, (long)S * 512);
    }
    return;
  }

  // -------- fallback path: round-1 verified --------
  const long ST = (long)6 * B * H;
  float* ws    = (float*)d_ws;
  float* out3  = ws;
  float* hbuf0 = out3 + 3 * OUT1;
  float* hbuf1 = hbuf0 + ST;
  float* cbuf  = hbuf1 + ST;
  float* Ct    = cbuf + ST;
  float* Hm    = Ct + OUT1;
  float* Ab    = Hm + (long)B * S * S;

  init_state<<<(6 * B * H + 255) / 256, 256, 0, stream>>>(hQ, cQ, hC, cC, hC2, cC2, hbuf0, cbuf);

  for (int t = 0; t < S; ++t) {
    float* hr = (t & 1) ? hbuf1 : hbuf0;
    float* hw = (t & 1) ? hbuf0 : hbuf1;
    lstm_step<<<dim3(16, 2, 6), 256, 0, stream>>>(
        idxQ, idxC, idxC2, emb,
        Wih_f, Whh_f, bih_f, bhh_f, Wih_b, Whh_b, bih_b, bhh_b,
        hr, hw, cbuf, out3, t);
  }

  for (int p = 0; p < 2; ++p) {
    const float* Q  = out3;
    const float* C0 = out3 + (long)(1 + p) * OUT1;
    gemm_nt<true><<<dim3(8, 256, 1), 256, 0, stream>>>(
        C0, S1W, S1b, Ct, 512, 512, 512, 512, 0, 0, 0);
    gemm_nt<false><<<dim3(2, 2, B), 256, 0, stream>>>(
        Q, Ct, nullptr, Hm, 512, 512, 128, 512,
        (long)S * 512, (long)S * 512, (long)S * S);
    softmax_row<<<B * S, 64, 0, stream>>>(Hm, Ab);
    float* MQ = out + (long)(2 * p) * OUT1;
    gemm_nn<<<dim3(8, 2, B), 256, 0, stream>>>(
        Ab, Q, MQ, 128, 512, 512, 128,
        (long)S * S, (long)S * 512, (long)S * 512);
    softmax_colT<<<B * S, 64, 0, stream>>>(Hm, Ab);
    float* MC = out + (long)(2 * p + 1) * OUT1;
    gemm_nn<<<dim3(8, 2, B), 256, 0, stream>>>(
        Ab, MQ, MC, 128, 512, 512, 128,
        (long)S * S, (long)S * 512, (long)S * 512);
  }
}

// Round 7
// 2497.708 us; speedup vs baseline: 12.3715x; 1.2933x over previous
//
#include <hip/hip_runtime.h>
#include <math.h>

namespace {

constexpr int S = 128;   // seq
constexpr int B = 128;   // batch
constexpr int E = 256;   // embed
constexpr int H = 256;   // hidden

typedef unsigned short u16;
typedef __attribute__((ext_vector_type(8))) short short8v;   // 8 bf16
typedef __attribute__((ext_vector_type(4))) float f32x4;

__device__ __forceinline__ float sigmoidf(float x) { return 1.0f / (1.0f + expf(-x)); }
__device__ __forceinline__ u16 bf16rnd(float x) {
  unsigned u = __float_as_uint(x);
  return (u16)((u + 0x7FFFu + ((u >> 16) & 1u)) >> 16);
}
__device__ __forceinline__ float bf2f(u16 v) { return __uint_as_float(((unsigned)v) << 16); }
__device__ __forceinline__ void split2(float x, u16& h, u16& l) {
  h = bf16rnd(x);
  l = bf16rnd(x - bf2f(h));
}
// gate-interleaved column mapping: col c in [0,1024) -> original W row
__device__ __forceinline__ int gcol_of(int c) {
  return ((c >> 4) & 3) * 256 + ((c & 15) + ((c >> 6) << 4));
}

// ================== split / prep kernels ==================

__global__ void split_pair(const float* __restrict__ src, u16* __restrict__ h,
                           u16* __restrict__ l, long n) {
  long i = (long)blockIdx.x * 256 + threadIdx.x;
  if (i < n) split2(src[i], h[i], l[i]);
}

__global__ void split_w_int(const float* __restrict__ W, u16* __restrict__ h,
                            u16* __restrict__ l) {
  int i = blockIdx.x * 256 + threadIdx.x;   // 1024*256
  int c = i >> 8, k = i & 255;
  split2(W[gcol_of(c) * 256 + k], h[i], l[i]);
}

__global__ void make_bint(const float* __restrict__ bih, const float* __restrict__ bhh,
                          float* __restrict__ bint) {
  int c = blockIdx.x * 256 + threadIdx.x;   // 1024
  int g = gcol_of(c);
  bint[c] = bih[g] + bhh[g];
}

__global__ void init_hc(const float* hQ, const float* cQ, const float* hC, const float* cC,
                        const float* hC2, const float* cC2,
                        u16* hH, u16* hL, float* cst) {
  int i = blockIdx.x * 256 + threadIdx.x;
  if (i >= 6 * B * H) return;
  int z = i / (B * H);
  int rem = i - z * (B * H);
  int input = z >> 1, dir = z & 1;
  const float* hs = input == 0 ? hQ : (input == 1 ? hC : hC2);
  const float* cs = input == 0 ? cQ : (input == 1 ? cC : cC2);
  split2(hs[dir * B * H + rem], hH[i], hL[i]);
  cst[i] = cs[dir * B * H + rem];
}

__global__ void zero_gen(int* gen) {
  if (threadIdx.x < 6) gen[threadIdx.x * 256] = 0;   // 1KB-padded counters
}

// ================== MFMA split-bf16 GEMM kernels ==================
// 256 thr = 4 waves (2x2), block tile 128x128, wave tile 64x64
// = 4x4 MFMA 16x16x32 tiles, K staged in chunks of 32, LDS pitch 40 bf16.
// Fragment maps (gfx950 mfma_f32_16x16x32_bf16):
//   A: row = lane&15, k = (lane>>4)*8 + j    B: col = lane&15, same k
//   D: row = (lane>>4)*4 + reg, col = lane&15   [m89-verified]

#define MFMA_PROLOG                                        \
  const int tid = threadIdx.x;                             \
  const int wave = tid >> 6, lane = tid & 63;              \
  const int wr = wave >> 1, wc = wave & 1;                 \
  const int lrow = lane & 15, lk = lane >> 4;              \
  f32x4 acc[4][4];

#define MFMA_ZERO_ACC                                      \
  _Pragma("unroll") for (int a_ = 0; a_ < 4; ++a_)         \
  _Pragma("unroll") for (int b_ = 0; b_ < 4; ++b_)         \
      acc[a_][b_] = (f32x4){0.f, 0.f, 0.f, 0.f};

#define MFMA_INNER                                                             \
  __syncthreads();                                                             \
  short8v ah[4], al[4];                                                        \
  _Pragma("unroll") for (int mt = 0; mt < 4; ++mt) {                           \
    int r_ = wr * 64 + mt * 16 + lrow;                                         \
    ah[mt] = *(const short8v*)&Ah[r_ * 40 + lk * 8];                           \
    al[mt] = *(const short8v*)&Al[r_ * 40 + lk * 8];                           \
  }                                                                            \
  _Pragma("unroll") for (int nt = 0; nt < 4; ++nt) {                           \
    int c_ = wc * 64 + nt * 16 + lrow;                                         \
    short8v bh = *(const short8v*)&Bh[c_ * 40 + lk * 8];                       \
    short8v bl = *(const short8v*)&Bl[c_ * 40 + lk * 8];                       \
    _Pragma("unroll") for (int mt = 0; mt < 4; ++mt) {                         \
      acc[mt][nt] = __builtin_amdgcn_mfma_f32_16x16x32_bf16(ah[mt], bh, acc[mt][nt], 0, 0, 0); \
      acc[mt][nt] = __builtin_amdgcn_mfma_f32_16x16x32_bf16(ah[mt], bl, acc[mt][nt], 0, 0, 0); \
      acc[mt][nt] = __builtin_amdgcn_mfma_f32_16x16x32_bf16(al[mt], bh, acc[mt][nt], 0, 0, 0); \
    }                                                                          \
  }

// ---- input projection: gi fp32 col-major [z][64t][1024 col][128 row] ----
// grid (8, 64, 6), block 256. phase selects which 64-t half per direction.
__global__ __launch_bounds__(256) void proj_mfma(
    const int* __restrict__ idxQ, const int* __restrict__ idxC, const int* __restrict__ idxC2,
    const u16* __restrict__ embH, const u16* __restrict__ embL,
    const u16* __restrict__ wHf, const u16* __restrict__ wLf,
    const u16* __restrict__ wHb, const u16* __restrict__ wLb,
    const float* __restrict__ bintf, const float* __restrict__ bintb,
    float* __restrict__ gi, int phase)
{
  const int z = blockIdx.z, input = z >> 1, dir = z & 1;
  const int n0 = blockIdx.x * 128;
  const int tl = blockIdx.y;            // local t-index within phase
  const int tb = (dir == 0) ? phase * 64 + tl : (64 - phase * 64) + tl;  // global t_eff block
  const int* idx = input == 0 ? idxQ : (input == 1 ? idxC : idxC2);
  const u16* wH = dir ? wHb : wHf;
  const u16* wL = dir ? wLb : wLf;
  const float* bint = dir ? bintb : bintf;

  __shared__ __align__(16) short Ah[128 * 40], Al[128 * 40], Bh[128 * 40], Bl[128 * 40];
  __shared__ int tok[128];
  MFMA_PROLOG
  if (tid < 128) tok[tid] = idx[tb * B + tid];
  MFMA_ZERO_ACC

  for (int kb = 0; kb < E; kb += 32) {
    __syncthreads();
#pragma unroll
    for (int i = 0; i < 2; ++i) {
      int e = i * 256 + tid;
      int r = e >> 2, kg = e & 3;
      long abase = (long)tok[r] * E + kb + kg * 8;
      *(short8v*)&Ah[r * 40 + kg * 8] = *(const short8v*)(embH + abase);
      *(short8v*)&Al[r * 40 + kg * 8] = *(const short8v*)(embL + abase);
      long bbase = (long)(n0 + r) * E + kb + kg * 8;
      *(short8v*)&Bh[r * 40 + kg * 8] = *(const short8v*)(wH + bbase);
      *(short8v*)&Bl[r * 40 + kg * 8] = *(const short8v*)(wL + bbase);
    }
    MFMA_INNER
  }

  float* gp = gi + ((long)z * 64 + tl) * 1024 * 128;
#pragma unroll
  for (int mt = 0; mt < 4; ++mt)
#pragma unroll
    for (int nt = 0; nt < 4; ++nt) {
      int c = n0 + wc * 64 + nt * 16 + lrow;
      float bv = bint[c];
      f32x4 v = acc[mt][nt];
      v.x += bv; v.y += bv; v.z += bv; v.w += bv;
      int rowb = wr * 64 + mt * 16 + lk * 4;
      *(f32x4*)&gp[(long)c * 128 + rowb] = v;
    }
}

// ---- persistent LSTM: 64 steps per launch, per-z 16-block barrier ----
// 96 blocks = 6 z * 16 nb (64 interleaved cols each); 256 thr = 4 waves over m.
// Wave tile 32m x 64n: mt 0..1, nt 0..3 (nt == gate). Whh slice LDS-resident.
__global__ __launch_bounds__(256) void lstm_persist(
    const u16* __restrict__ whHf, const u16* __restrict__ whLf,
    const u16* __restrict__ whHb, const u16* __restrict__ whLb,
    const float* __restrict__ gi,
    u16* __restrict__ hH, u16* __restrict__ hL, float* __restrict__ cst,
    u16* __restrict__ out3h, u16* __restrict__ out3l,
    int* __restrict__ gen, int phase)
{
  const int bx = blockIdx.x;
  const int z = bx >> 4, nb = bx & 15;
  const int input = z >> 1, dir = z & 1;
  const int n0c = nb * 64;                 // global interleaved col base
  const int tid = threadIdx.x;
  const int wave = tid >> 6, lane = tid & 63;
  const int lrow = lane & 15, lk = lane >> 4;
  const int wr = wave;                     // 4 waves over m: rows wr*32..+31
  const u16* wHp = dir ? whHb : whHf;
  const u16* wLp = dir ? whLb : whLf;

  __shared__ __align__(16) short WlH[64 * 264], WlL[64 * 264];  // pitch 264: 2-way reads (free)

  // one-time Whh slice load (amortized over 64 steps)
#pragma unroll
  for (int i = 0; i < 8; ++i) {
    int e = i * 256 + tid;                 // 2048 chunks of 8 bf16
    int c = e >> 5, kc = e & 31;
    *(short8v*)&WlH[c * 264 + kc * 8] = *(const short8v*)(wHp + (long)(n0c + c) * 256 + kc * 8);
    *(short8v*)&WlL[c * 264 + kc * 8] = *(const short8v*)(wLp + (long)(n0c + c) * 256 + kc * 8);
  }
  __syncthreads();

  const long HS = (long)6 * B * H;
  const long zb = (long)z * B * H;
  const int u = nb * 16 + lrow;            // unit (0..255)
  int* genz = gen + z * 256;               // 1KB padded
  u16* o3h = out3h + (long)input * B * S * 512;
  u16* o3l = out3l + (long)input * B * S * 512;

  for (int tl = 0; tl < 64; ++tl) {
    const int t_global = phase * 64 + tl;
    const int t_eff = dir ? (S - 1 - t_global) : t_global;
    const int local = (dir == 0) ? tl : 63 - tl;
    const int par = t_global & 1;

    // gi prefetch (static data; issue before barrier wait)
    f32x4 gv[2][4];
    {
      const float* gp = gi + ((long)z * 64 + local) * 1024 * 128;
#pragma unroll
      for (int mt = 0; mt < 2; ++mt)
#pragma unroll
        for (int nt = 0; nt < 4; ++nt) {
          int c = n0c + nt * 16 + lrow;
          int rowb = wr * 32 + mt * 16 + lk * 4;
          gv[mt][nt] = *(const f32x4*)&gp[(long)c * 128 + rowb];
        }
    }

    // wait for previous step's h (16 arrivals per z per step)
    if (tl > 0) {
      if (tid == 0) {
        const int target = 16 * tl;
        while (__hip_atomic_load(genz, __ATOMIC_ACQUIRE, __HIP_MEMORY_SCOPE_AGENT) < target) {
          __builtin_amdgcn_s_sleep(2);
        }
      }
      __syncthreads();
    }

    const u16* hrH = hH + (long)par * HS + zb;
    const u16* hrL = hL + (long)par * HS + zb;

    f32x4 acc[2][4];
#pragma unroll
    for (int mt = 0; mt < 2; ++mt)
#pragma unroll
      for (int nt = 0; nt < 4; ++nt) acc[mt][nt] = gv[mt][nt];

#pragma unroll
    for (int kb = 0; kb < 8; ++kb) {
      short8v ah[2], al[2];
#pragma unroll
      for (int mt = 0; mt < 2; ++mt) {
        long ho = (long)(wr * 32 + mt * 16 + lrow) * 256 + kb * 32 + lk * 8;
        ah[mt] = *(const short8v*)(hrH + ho);
        al[mt] = *(const short8v*)(hrL + ho);
      }
#pragma unroll
      for (int nt = 0; nt < 4; ++nt) {
        int c = nt * 16 + lrow;
        short8v bh = *(const short8v*)&WlH[c * 264 + kb * 32 + lk * 8];
        short8v bl = *(const short8v*)&WlL[c * 264 + kb * 32 + lk * 8];
#pragma unroll
        for (int mt = 0; mt < 2; ++mt) {
          acc[mt][nt] = __builtin_amdgcn_mfma_f32_16x16x32_bf16(ah[mt], bh, acc[mt][nt], 0, 0, 0);
          acc[mt][nt] = __builtin_amdgcn_mfma_f32_16x16x32_bf16(ah[mt], bl, acc[mt][nt], 0, 0, 0);
          acc[mt][nt] = __builtin_amdgcn_mfma_f32_16x16x32_bf16(al[mt], bh, acc[mt][nt], 0, 0, 0);
        }
      }
    }

    // epilogue: nt == gate (i,f,g,o); unit u fixed per thread
    float* cz = cst + zb;
    u16* hwH = hH + (long)(par ^ 1) * HS + zb;
    u16* hwL = hL + (long)(par ^ 1) * HS + zb;
#pragma unroll
    for (int mt = 0; mt < 2; ++mt)
#pragma unroll
      for (int rg = 0; rg < 4; ++rg) {
        int row = wr * 32 + mt * 16 + lk * 4 + rg;
        float ig = sigmoidf(acc[mt][0][rg]);
        float fg = sigmoidf(acc[mt][1][rg]);
        float gg = tanhf(acc[mt][2][rg]);
        float og = sigmoidf(acc[mt][3][rg]);
        long ci = (long)row * H + u;
        float cn = fg * cz[ci] + ig * gg;
        cz[ci] = cn;
        float hn = og * tanhf(cn);
        u16 hh, hl;
        split2(hn, hh, hl);
        hwH[ci] = hh;
        hwL[ci] = hl;
        long oi = ((long)row * S + t_eff) * 512 + dir * 256 + u;
        o3h[oi] = hh;
        o3l[oi] = hl;
      }

    // publish: drain this thread's stores to L2, block-align, one release add
    asm volatile("s_waitcnt vmcnt(0)" ::: "memory");
    __syncthreads();
    if (tid == 0) {
      __hip_atomic_fetch_add(genz, 1, __ATOMIC_RELEASE, __HIP_MEMORY_SCOPE_AGENT);
    }
  }
}

// ---- Ct = tanh(C0 @ S1W^T + S1b), output split hi/lo ----
// grid (4, 128), block 256. M=16384, N=512, K=512.
__global__ __launch_bounds__(256) void ct_mfma(
    const u16* __restrict__ aH, const u16* __restrict__ aL,
    const u16* __restrict__ s1H, const u16* __restrict__ s1L,
    const float* __restrict__ s1b,
    u16* __restrict__ ctH, u16* __restrict__ ctL)
{
  const int n0 = blockIdx.x * 128, m0 = blockIdx.y * 128;
  __shared__ __align__(16) short Ah[128 * 40], Al[128 * 40], Bh[128 * 40], Bl[128 * 40];
  MFMA_PROLOG
  MFMA_ZERO_ACC

  for (int kb = 0; kb < 512; kb += 32) {
    __syncthreads();
#pragma unroll
    for (int i = 0; i < 2; ++i) {
      int e = i * 256 + tid;
      int r = e >> 2, kg = e & 3;
      long abase = (long)(m0 + r) * 512 + kb + kg * 8;
      *(short8v*)&Ah[r * 40 + kg * 8] = *(const short8v*)(aH + abase);
      *(short8v*)&Al[r * 40 + kg * 8] = *(const short8v*)(aL + abase);
      long bbase = (long)(n0 + r) * 512 + kb + kg * 8;
      *(short8v*)&Bh[r * 40 + kg * 8] = *(const short8v*)(s1H + bbase);
      *(short8v*)&Bl[r * 40 + kg * 8] = *(const short8v*)(s1L + bbase);
    }
    MFMA_INNER
  }

#pragma unroll
  for (int mt = 0; mt < 4; ++mt)
#pragma unroll
    for (int nt = 0; nt < 4; ++nt) {
      int c = n0 + wc * 64 + nt * 16 + lrow;
      float bv = s1b[c];
#pragma unroll
      for (int rg = 0; rg < 4; ++rg) {
        long m = m0 + wr * 64 + mt * 16 + lk * 4 + rg;
        u16 hh, ll;
        split2(tanhf(acc[mt][nt][rg] + bv), hh, ll);
        ctH[m * 512 + c] = hh;
        ctL[m * 512 + c] = ll;
      }
    }
}

// ---- Hm[b] = Q[b] @ Ct[b]^T (fp32 out) ----
__global__ __launch_bounds__(256) void hm_mfma(
    const u16* __restrict__ qH, const u16* __restrict__ qL,
    const u16* __restrict__ ctH, const u16* __restrict__ ctL,
    float* __restrict__ Hm)
{
  const int bb = blockIdx.x;
  const u16* aH = qH + (long)bb * S * 512;
  const u16* aL = qL + (long)bb * S * 512;
  const u16* bH = ctH + (long)bb * S * 512;
  const u16* bL = ctL + (long)bb * S * 512;
  __shared__ __align__(16) short Ah[128 * 40], Al[128 * 40], Bh[128 * 40], Bl[128 * 40];
  MFMA_PROLOG
  MFMA_ZERO_ACC

  for (int kb = 0; kb < 512; kb += 32) {
    __syncthreads();
#pragma unroll
    for (int i = 0; i < 2; ++i) {
      int e = i * 256 + tid;
      int r = e >> 2, kg = e & 3;
      long base = (long)r * 512 + kb + kg * 8;
      *(short8v*)&Ah[r * 40 + kg * 8] = *(const short8v*)(aH + base);
      *(short8v*)&Al[r * 40 + kg * 8] = *(const short8v*)(aL + base);
      *(short8v*)&Bh[r * 40 + kg * 8] = *(const short8v*)(bH + base);
      *(short8v*)&Bl[r * 40 + kg * 8] = *(const short8v*)(bL + base);
    }
    MFMA_INNER
  }

  float* out = Hm + (long)bb * S * S;
#pragma unroll
  for (int mt = 0; mt < 4; ++mt)
#pragma unroll
    for (int nt = 0; nt < 4; ++nt) {
      int c = wc * 64 + nt * 16 + lrow;
#pragma unroll
      for (int rg = 0; rg < 4; ++rg) {
        int m = wr * 64 + mt * 16 + lk * 4 + rg;
        out[(long)m * S + c] = acc[mt][nt][rg];
      }
    }
}

// ---- Qt[b][c][t] planes from o3 planes [b][t][512] (LDS tile transpose) ----
// grid (8 cblk, 2 tblk, 128 b), block 256.
__global__ void transpose_qt(const u16* __restrict__ o3h, const u16* __restrict__ o3l,
                             u16* __restrict__ qth, u16* __restrict__ qtl) {
  const int b = blockIdx.z;
  const int c0 = blockIdx.x * 64, t0 = blockIdx.y * 64;
  __shared__ u16 tile[64][72];
  const int tid = threadIdx.x;
  for (int pl = 0; pl < 2; ++pl) {
    const u16* src = (pl ? o3l : o3h) + (long)b * S * 512;
    u16* dst = (pl ? qtl : qth) + (long)b * 512 * 128;
    __syncthreads();
#pragma unroll
    for (int i = 0; i < 2; ++i) {
      int e = i * 256 + tid;
      int r = e >> 3, sg = e & 7;
      *(short8v*)&tile[r][sg * 8] = *(const short8v*)(src + (long)(t0 + r) * 512 + c0 + sg * 8);
    }
    __syncthreads();
#pragma unroll
    for (int i = 0; i < 2; ++i) {
      int e = i * 256 + tid;
      int c = e >> 3, sg = e & 7;
      short8v v;
#pragma unroll
      for (int j = 0; j < 8; ++j) v[j] = tile[sg * 8 + j][c];
      *(short8v*)(dst + (long)(c0 + c) * 128 + t0 + sg * 8) = v;
    }
  }
}

// ---- pq_mfma: C[b][128][512] = P[b][128x128] @ Bt[b][512x128]^T (K = t dim) ----
// A planes [b][m][k] pitch 128; B planes [b][c][k] pitch 128. grid (4, 1, 128).
// WRITE_T: also emit C^T as bf16 hi/lo planes [b][c][m] (for the MC chain).
template <bool WRITE_T>
__global__ __launch_bounds__(256) void pq_mfma(
    const u16* __restrict__ pH, const u16* __restrict__ pL,
    const u16* __restrict__ btH, const u16* __restrict__ btL,
    float* __restrict__ Cout, u16* __restrict__ tH, u16* __restrict__ tL)
{
  const int bb = blockIdx.z, n0 = blockIdx.x * 128;
  const u16* aHp = pH + (long)bb * 128 * 128;
  const u16* aLp = pL + (long)bb * 128 * 128;
  const u16* bHp = btH + ((long)bb * 512 + n0) * 128;
  const u16* bLp = btL + ((long)bb * 512 + n0) * 128;
  __shared__ __align__(16) short Ah[128 * 40], Al[128 * 40], Bh[128 * 40], Bl[128 * 40];
  MFMA_PROLOG
  MFMA_ZERO_ACC

  for (int kb = 0; kb < 128; kb += 32) {
    __syncthreads();
#pragma unroll
    for (int i = 0; i < 2; ++i) {
      int e = i * 256 + tid;
      int r = e >> 2, kg = e & 3;
      long base = (long)r * 128 + kb + kg * 8;
      *(short8v*)&Ah[r * 40 + kg * 8] = *(const short8v*)(aHp + base);
      *(short8v*)&Al[r * 40 + kg * 8] = *(const short8v*)(aLp + base);
      *(short8v*)&Bh[r * 40 + kg * 8] = *(const short8v*)(bHp + base);
      *(short8v*)&Bl[r * 40 + kg * 8] = *(const short8v*)(bLp + base);
    }
    MFMA_INNER
  }

  float* co = Cout + (long)bb * 128 * 512;
#pragma unroll
  for (int mt = 0; mt < 4; ++mt)
#pragma unroll
    for (int nt = 0; nt < 4; ++nt) {
      int c = n0 + wc * 64 + nt * 16 + lrow;
#pragma unroll
      for (int rg = 0; rg < 4; ++rg) {
        int m = wr * 64 + mt * 16 + lk * 4 + rg;
        float v = acc[mt][nt][rg];
        co[(long)m * 512 + c] = v;
        if (WRITE_T) {
          u16 hh, ll;
          split2(v, hh, ll);
          tH[((long)bb * 512 + c) * 128 + m] = hh;
          tL[((long)bb * 512 + c) * 128 + m] = ll;
        }
      }
    }
}

// ---------------- softmaxes ----------------
__global__ void softmax_row_bf(const float* __restrict__ Hm, u16* __restrict__ ph,
                               u16* __restrict__ pl) {
  const int row = blockIdx.x;
  const float* p = Hm + (long)row * S;
  const int l = threadIdx.x;
  float v0 = p[l], v1 = p[l + 64];
  float m = fmaxf(v0, v1);
#pragma unroll
  for (int o = 32; o > 0; o >>= 1) m = fmaxf(m, __shfl_xor(m, o));
  float e0 = expf(v0 - m), e1 = expf(v1 - m);
  float s = e0 + e1;
#pragma unroll
  for (int o = 32; o > 0; o >>= 1) s += __shfl_xor(s, o);
  float inv = 1.0f / s;
  u16 hh, ll;
  split2(e0 * inv, hh, ll);
  ph[(long)row * S + l] = hh; pl[(long)row * S + l] = ll;
  split2(e1 * inv, hh, ll);
  ph[(long)row * S + l + 64] = hh; pl[(long)row * S + l + 64] = ll;
}

__global__ void softmax_colT_bf(const float* __restrict__ Hm, u16* __restrict__ ph,
                                u16* __restrict__ pl) {
  const int b = blockIdx.x >> 7;
  const int col = blockIdx.x & 127;
  const float* p = Hm + (long)b * S * S + col;
  const int l = threadIdx.x;
  float v0 = p[(long)l * S], v1 = p[(long)(l + 64) * S];
  float m = fmaxf(v0, v1);
#pragma unroll
  for (int o = 32; o > 0; o >>= 1) m = fmaxf(m, __shfl_xor(m, o));
  float e0 = expf(v0 - m), e1 = expf(v1 - m);
  float s = e0 + e1;
#pragma unroll
  for (int o = 32; o > 0; o >>= 1) s += __shfl_xor(s, o);
  float inv = 1.0f / s;
  long q = ((long)b * S + col) * S;
  u16 hh, ll;
  split2(e0 * inv, hh, ll);
  ph[q + l] = hh; pl[q + l] = ll;
  split2(e1 * inv, hh, ll);
  ph[q + l + 64] = hh; pl[q + l + 64] = ll;
}

// fp32 softmaxes for the fallback path
__global__ void softmax_row(const float* __restrict__ Hm, float* __restrict__ A) {
  const int row = blockIdx.x;
  const float* p = Hm + (long)row * S;
  const int l = threadIdx.x;
  float v0 = p[l], v1 = p[l + 64];
  float m = fmaxf(v0, v1);
#pragma unroll
  for (int o = 32; o > 0; o >>= 1) m = fmaxf(m, __shfl_xor(m, o));
  float e0 = expf(v0 - m), e1 = expf(v1 - m);
  float s = e0 + e1;
#pragma unroll
  for (int o = 32; o > 0; o >>= 1) s += __shfl_xor(s, o);
  float inv = 1.0f / s;
  float* q = A + (long)row * S;
  q[l] = e0 * inv; q[l + 64] = e1 * inv;
}

__global__ void softmax_colT(const float* __restrict__ Hm, float* __restrict__ A) {
  const int b = blockIdx.x >> 7;
  const int col = blockIdx.x & 127;
  const float* p = Hm + (long)b * S * S + col;
  const int l = threadIdx.x;
  float v0 = p[(long)l * S], v1 = p[(long)(l + 64) * S];
  float m = fmaxf(v0, v1);
#pragma unroll
  for (int o = 32; o > 0; o >>= 1) m = fmaxf(m, __shfl_xor(m, o));
  float e0 = expf(v0 - m), e1 = expf(v1 - m);
  float s = e0 + e1;
#pragma unroll
  for (int o = 32; o > 0; o >>= 1) s += __shfl_xor(s, o);
  float inv = 1.0f / s;
  float* q = A + ((long)b * S + col) * S;
  q[l] = e0 * inv; q[l + 64] = e1 * inv;
}

// ================== FALLBACK PATH (round-1, verified) ==================

__global__ void init_state(const float* hQ, const float* cQ,
                           const float* hC, const float* cC,
                           const float* hC2, const float* cC2,
                           float* h0, float* c0) {
  int i = blockIdx.x * 256 + threadIdx.x;
  if (i >= 6 * B * H) return;
  int z = i / (B * H);
  int rem = i - z * (B * H);
  int input = z >> 1, dir = z & 1;
  const float* hs = input == 0 ? hQ : (input == 1 ? hC : hC2);
  const float* cs = input == 0 ? cQ : (input == 1 ? cC : cC2);
  h0[i] = hs[dir * B * H + rem];
  c0[i] = cs[dir * B * H + rem];
}

__global__ __launch_bounds__(256) void lstm_step(
    const int* __restrict__ idxQ, const int* __restrict__ idxC, const int* __restrict__ idxC2,
    const float* __restrict__ emb,
    const float* __restrict__ Wih_f, const float* __restrict__ Whh_f,
    const float* __restrict__ bih_f, const float* __restrict__ bhh_f,
    const float* __restrict__ Wih_b, const float* __restrict__ Whh_b,
    const float* __restrict__ bih_b, const float* __restrict__ bhh_b,
    const float* __restrict__ hread, float* __restrict__ hwrite,
    float* __restrict__ cstate, float* __restrict__ out3, int t)
{
  const int z = blockIdx.z;
  const int input = z >> 1, dir = z & 1;
  const int u0 = blockIdx.x * 16;
  const int b0 = blockIdx.y * 64;
  const int t_eff = dir ? (S - 1 - t) : t;
  const int* idx = input == 0 ? idxQ : (input == 1 ? idxC : idxC2);
  const float* Wih = dir ? Wih_b : Wih_f;
  const float* Whh = dir ? Whh_b : Whh_f;
  const float* bih = dir ? bih_b : bih_f;
  const float* bhh = dir ? bhh_b : bhh_f;

  __shared__ float Alds[64][68];
  __shared__ float Wl[64][68];
  __shared__ int tok[64];

  const int tid = threadIdx.x;
  if (tid < 64) tok[tid] = idx[t_eff * B + b0 + tid];

  const int uu = tid & 15;
  const int rg = tid >> 4;
  const int u = u0 + uu;

  float acc[4][4];
#pragma unroll
  for (int ri = 0; ri < 4; ++ri)
#pragma unroll
    for (int g = 0; g < 4; ++g)
      acc[ri][g] = bih[g * 256 + u] + bhh[g * 256 + u];

  for (int kc = 0; kc < 8; ++kc) {
    __syncthreads();
    if (kc < 4) {
      const int kb = kc * 64;
#pragma unroll
      for (int i = 0; i < 16; ++i) {
        int e = i * 256 + tid;
        int kk = e & 63, r = e >> 6;
        Alds[r][kk] = emb[(long)tok[r] * E + kb + kk];
      }
    } else {
      const int kb = (kc - 4) * 64;
      const float* hs = hread + ((long)z * B + b0) * H + kb;
#pragma unroll
      for (int i = 0; i < 16; ++i) {
        int e = i * 256 + tid;
        int kk = e & 63, r = e >> 6;
        Alds[r][kk] = hs[r * H + kk];
      }
    }
    {
      const float* Wsrc = (kc < 4) ? Wih : Whh;
      const int kb = (kc & 3) * 64;
#pragma unroll
      for (int i = 0; i < 16; ++i) {
        int e = i * 256 + tid;
        int kk = e & 63, c = e >> 6;
        int gcol = (c >> 4) * 256 + u0 + (c & 15);
        Wl[c][kk] = Wsrc[(long)gcol * H + kb + kk];
      }
    }
    __syncthreads();
#pragma unroll
    for (int k4 = 0; k4 < 64; k4 += 4) {
      float4 a[4], w[4];
#pragma unroll
      for (int ri = 0; ri < 4; ++ri) a[ri] = *(const float4*)&Alds[rg * 4 + ri][k4];
#pragma unroll
      for (int g = 0; g < 4; ++g) w[g] = *(const float4*)&Wl[g * 16 + uu][k4];
#pragma unroll
      for (int ri = 0; ri < 4; ++ri)
#pragma unroll
        for (int g = 0; g < 4; ++g)
          acc[ri][g] += a[ri].x * w[g].x + a[ri].y * w[g].y
                      + a[ri].z * w[g].z + a[ri].w * w[g].w;
    }
  }

  float* cs = cstate + (long)z * B * H;
  float* hw = hwrite + (long)z * B * H;
  float* op = out3 + (long)input * B * S * 2 * H;
#pragma unroll
  for (int ri = 0; ri < 4; ++ri) {
    int b = b0 + rg * 4 + ri;
    float ig = sigmoidf(acc[ri][0]);
    float fg = sigmoidf(acc[ri][1]);
    float gg = tanhf(acc[ri][2]);
    float og = sigmoidf(acc[ri][3]);
    float cn = fg * cs[b * H + u] + ig * gg;
    float hn = og * tanhf(cn);
    cs[b * H + u] = cn;
    hw[b * H + u] = hn;
    op[((long)b * S + t_eff) * (2 * H) + dir * H + u] = hn;
  }
}

template <bool TANH>
__global__ __launch_bounds__(256) void gemm_nt(
    const float* __restrict__ A, const float* __restrict__ B_,
    const float* __restrict__ bias, float* __restrict__ C,
    int lda, int ldb, int ldc, int K, long sA, long sB, long sC)
{
  A += blockIdx.z * sA; B_ += blockIdx.z * sB; C += blockIdx.z * sC;
  const int n0 = blockIdx.x * 64, m0 = blockIdx.y * 64;
  __shared__ float Alds[64][68], Blds[64][68];
  const int tid = threadIdx.x, uu = tid & 15, rg = tid >> 4;
  float acc[4][4] = {};
  for (int kb = 0; kb < K; kb += 64) {
    __syncthreads();
#pragma unroll
    for (int i = 0; i < 16; ++i) {
      int e = i * 256 + tid;
      int kk = e & 63, r = e >> 6;
      Alds[r][kk] = A[(long)(m0 + r) * lda + kb + kk];
      Blds[r][kk] = B_[(long)(n0 + r) * ldb + kb + kk];
    }
    __syncthreads();
#pragma unroll
    for (int k4 = 0; k4 < 64; k4 += 4) {
      float4 a[4], w[4];
#pragma unroll
      for (int ri = 0; ri < 4; ++ri) a[ri] = *(const float4*)&Alds[rg * 4 + ri][k4];
#pragma unroll
      for (int ci = 0; ci < 4; ++ci) w[ci] = *(const float4*)&Blds[ci * 16 + uu][k4];
#pragma unroll
      for (int ri = 0; ri < 4; ++ri)
#pragma unroll
        for (int ci = 0; ci < 4; ++ci)
          acc[ri][ci] += a[ri].x * w[ci].x + a[ri].y * w[ci].y
                       + a[ri].z * w[ci].z + a[ri].w * w[ci].w;
    }
  }
#pragma unroll
  for (int ri = 0; ri < 4; ++ri) {
    int m = m0 + rg * 4 + ri;
#pragma unroll
    for (int ci = 0; ci < 4; ++ci) {
      int n = n0 + ci * 16 + uu;
      float v = acc[ri][ci];
      if (bias) v += bias[n];
      if (TANH) v = tanhf(v);
      C[(long)m * ldc + n] = v;
    }
  }
}

__global__ __launch_bounds__(256) void gemm_nn(
    const float* __restrict__ A, const float* __restrict__ B_,
    float* __restrict__ C,
    int lda, int ldb, int ldc, int K, long sA, long sB, long sC)
{
  A += blockIdx.z * sA; B_ += blockIdx.z * sB; C += blockIdx.z * sC;
  const int n0 = blockIdx.x * 64, m0 = blockIdx.y * 64;
  __shared__ float Alds[64][68];
  __shared__ float Blds[64][68];
  const int tid = threadIdx.x, uu = tid & 15, rg = tid >> 4;
  float acc[4][4] = {};
  for (int kb = 0; kb < K; kb += 64) {
    __syncthreads();
#pragma unroll
    for (int i = 0; i < 16; ++i) {
      int e = i * 256 + tid;
      int kk = e & 63, r = e >> 6;
      Alds[r][kk] = A[(long)(m0 + r) * lda + kb + kk];
      Blds[r][kk] = B_[(long)(kb + r) * ldb + n0 + kk];
    }
    __syncthreads();
#pragma unroll
    for (int kk = 0; kk < 64; ++kk) {
      float4 w = *(const float4*)&Blds[kk][uu * 4];
      float a0 = Alds[rg * 4 + 0][kk], a1 = Alds[rg * 4 + 1][kk];
      float a2 = Alds[rg * 4 + 2][kk], a3 = Alds[rg * 4 + 3][kk];
      acc[0][0] += a0 * w.x; acc[0][1] += a0 * w.y; acc[0][2] += a0 * w.z; acc[0][3] += a0 * w.w;
      acc[1][0] += a1 * w.x; acc[1][1] += a1 * w.y; acc[1][2] += a1 * w.z; acc[1][3] += a1 * w.w;
      acc[2][0] += a2 * w.x; acc[2][1] += a2 * w.y; acc[2][2] += a2 * w.z; acc[2][3] += a2 * w.w;
      acc[3][0] += a3 * w.x; acc[3][1] += a3 * w.y; acc[3][2] += a3 * w.z; acc[3][3] += a3 * w.w;
    }
  }
#pragma unroll
  for (int ri = 0; ri < 4; ++ri) {
    int m = m0 + rg * 4 + ri;
    float4 v = make_float4(acc[ri][0], acc[ri][1], acc[ri][2], acc[ri][3]);
    *(float4*)&C[(long)m * ldc + n0 + uu * 4] = v;
  }
}

}  // namespace

extern "C" void kernel_launch(void* const* d_in, const int* in_sizes, int n_in,
                              void* d_out, int out_size, void* d_ws, size_t ws_size,
                              hipStream_t stream) {
  const int* idxQ    = (const int*)d_in[1];
  const int* idxC    = (const int*)d_in[2];
  const int* idxC2   = (const int*)d_in[3];
  const float* hQ    = (const float*)d_in[4];
  const float* cQ    = (const float*)d_in[5];
  const float* hC    = (const float*)d_in[6];
  const float* cC    = (const float*)d_in[7];
  const float* hC2   = (const float*)d_in[8];
  const float* cC2   = (const float*)d_in[9];
  const float* emb   = (const float*)d_in[10];
  const float* Wih_f = (const float*)d_in[11];
  const float* Whh_f = (const float*)d_in[12];
  const float* bih_f = (const float*)d_in[13];
  const float* bhh_f = (const float*)d_in[14];
  const float* Wih_b = (const float*)d_in[15];
  const float* Whh_b = (const float*)d_in[16];
  const float* bih_b = (const float*)d_in[17];
  const float* bhh_b = (const float*)d_in[18];
  const float* S1W   = (const float*)d_in[19];
  const float* S1b   = (const float*)d_in[20];
  float* out = (float*)d_out;

  const long V = 50000;
  const long OUT1 = (long)B * S * 2 * H;   // 8,388,608 floats per input

  // -------- fast-path workspace layout (bytes) --------
  size_t off = 0;
  auto alloc = [&](size_t bytes) { size_t o = off; off += (bytes + 255) & ~(size_t)255; return o; };
  const size_t o_gi   = alloc((size_t)6 * 64 * 1024 * 128 * 4);     // 201.3 MB fp32
  const size_t o_o3h  = alloc((size_t)3 * B * S * 512 * 2);
  const size_t o_o3l  = alloc((size_t)3 * B * S * 512 * 2);
  const size_t o_embH = alloc((size_t)V * E * 2);
  const size_t o_embL = alloc((size_t)V * E * 2);
  const size_t o_wihHf = alloc(1024 * 256 * 2), o_wihLf = alloc(1024 * 256 * 2);
  const size_t o_wihHb = alloc(1024 * 256 * 2), o_wihLb = alloc(1024 * 256 * 2);
  const size_t o_whhHf = alloc(1024 * 256 * 2), o_whhLf = alloc(1024 * 256 * 2);
  const size_t o_whhHb = alloc(1024 * 256 * 2), o_whhLb = alloc(1024 * 256 * 2);
  const size_t o_s1H  = alloc(512 * 512 * 2), o_s1L = alloc(512 * 512 * 2);
  const size_t o_bintf = alloc(1024 * 4), o_bintb = alloc(1024 * 4);
  const size_t o_hH   = alloc((size_t)2 * 6 * B * H * 2);
  const size_t o_hL   = alloc((size_t)2 * 6 * B * H * 2);
  const size_t o_cst  = alloc((size_t)6 * B * H * 4);
  const size_t o_gen  = alloc(6 * 256 * 4);
  const size_t need_fast = off;   // ~361 MB

  if (ws_size >= need_fast) {
    char* base = (char*)d_ws;
    float* gi = (float*)(base + o_gi);
    u16* o3h = (u16*)(base + o_o3h);
    u16* o3l = (u16*)(base + o_o3l);
    u16* embH = (u16*)(base + o_embH);
    u16* embL = (u16*)(base + o_embL);
    u16* wihHf = (u16*)(base + o_wihHf); u16* wihLf = (u16*)(base + o_wihLf);
    u16* wihHb = (u16*)(base + o_wihHb); u16* wihLb = (u16*)(base + o_wihLb);
    u16* whhHf = (u16*)(base + o_whhHf); u16* whhLf = (u16*)(base + o_whhLf);
    u16* whhHb = (u16*)(base + o_whhHb); u16* whhLb = (u16*)(base + o_whhLb);
    u16* s1H = (u16*)(base + o_s1H); u16* s1L = (u16*)(base + o_s1L);
    float* bintf = (float*)(base + o_bintf);
    float* bintb = (float*)(base + o_bintb);
    u16* hH = (u16*)(base + o_hH);
    u16* hL = (u16*)(base + o_hL);
    float* cst = (float*)(base + o_cst);
    int* gen = (int*)(base + o_gen);
    // attention scratch aliases gi (dead after last lstm_persist)
    char* gib = base + o_gi;
    u16* ctH = (u16*)gib;                                    // 16.8 MB
    u16* ctL = (u16*)(gib + 16777216);                       // 16.8 MB
    float* Hm = (float*)(gib + 2 * 16777216);                // 8.4 MB
    u16* Ph  = (u16*)(gib + 2 * 16777216 + 8388608);         // 4.2 MB
    u16* Pl  = (u16*)(gib + 2 * 16777216 + 8388608 + 4194304);
    u16* QtH = (u16*)(gib + 2 * 16777216 + 8388608 + 2 * 4194304);
    u16* QtL = (u16*)(gib + 3 * 16777216 + 8388608 + 2 * 4194304);
    u16* MQtH = (u16*)(gib + 4 * 16777216 + 8388608 + 2 * 4194304);
    u16* MQtL = (u16*)(gib + 5 * 16777216 + 8388608 + 2 * 4194304);

    // ---- prep ----
    split_pair<<<(int)((V * E + 255) / 256), 256, 0, stream>>>(emb, embH, embL, V * E);
    split_w_int<<<1024, 256, 0, stream>>>(Wih_f, wihHf, wihLf);
    split_w_int<<<1024, 256, 0, stream>>>(Wih_b, wihHb, wihLb);
    split_w_int<<<1024, 256, 0, stream>>>(Whh_f, whhHf, whhLf);
    split_w_int<<<1024, 256, 0, stream>>>(Whh_b, whhHb, whhLb);
    split_pair<<<1024, 256, 0, stream>>>(S1W, s1H, s1L, 512 * 512);
    make_bint<<<4, 256, 0, stream>>>(bih_f, bhh_f, bintf);
    make_bint<<<4, 256, 0, stream>>>(bih_b, bhh_b, bintb);
    init_hc<<<(6 * B * H + 255) / 256, 256, 0, stream>>>(hQ, cQ, hC, cC, hC2, cC2, hH, hL, cst);

    // ---- LSTM: 2 phases of {proj + 64-step persistent kernel} ----
    for (int phase = 0; phase < 2; ++phase) {
      proj_mfma<<<dim3(8, 64, 6), 256, 0, stream>>>(
          idxQ, idxC, idxC2, embH, embL,
          wihHf, wihLf, wihHb, wihLb, bintf, bintb, gi, phase);
      zero_gen<<<1, 64, 0, stream>>>(gen);
      {
        const u16* a0 = whhHf; const u16* a1 = whhLf;
        const u16* a2 = whhHb; const u16* a3 = whhLb;
        const float* a4 = gi; u16* a5 = hH; u16* a6 = hL;
        float* a7 = cst; u16* a8 = o3h; u16* a9 = o3l;
        int* a10 = gen; int a11 = phase;
        void* kargs[] = {(void*)&a0, (void*)&a1, (void*)&a2, (void*)&a3,
                         (void*)&a4, (void*)&a5, (void*)&a6, (void*)&a7,
                         (void*)&a8, (void*)&a9, (void*)&a10, (void*)&a11};
        hipLaunchCooperativeKernel((const void*)lstm_persist, dim3(96), dim3(256),
                                   kargs, 0, stream);
      }
    }

    // ---- attention ----
    transpose_qt<<<dim3(8, 2, 128), 256, 0, stream>>>(o3h, o3l, QtH, QtL);
    for (int p = 0; p < 2; ++p) {
      const u16* aH = o3h + (size_t)(1 + p) * B * S * 512;
      const u16* aL = o3l + (size_t)(1 + p) * B * S * 512;
      ct_mfma<<<dim3(4, 128), 256, 0, stream>>>(aH, aL, s1H, s1L, S1b, ctH, ctL);
      hm_mfma<<<128, 256, 0, stream>>>(o3h, o3l, ctH, ctL, Hm);
      softmax_row_bf<<<B * S, 64, 0, stream>>>(Hm, Ph, Pl);
      float* MQ = out + (long)(2 * p) * OUT1;
      pq_mfma<true><<<dim3(4, 1, 128), 256, 0, stream>>>(
          Ph, Pl, QtH, QtL, MQ, MQtH, MQtL);
      softmax_colT_bf<<<B * S, 64, 0, stream>>>(Hm, Ph, Pl);
      float* MC = out + (long)(2 * p + 1) * OUT1;
      pq_mfma<false><<<dim3(4, 1, 128), 256, 0, stream>>>(
          Ph, Pl, MQtH, MQtL, MC, nullptr, nullptr);
    }
    return;
  }

  // -------- fallback path: round-1 verified --------
  const long ST = (long)6 * B * H;
  float* ws    = (float*)d_ws;
  float* out3  = ws;
  float* hbuf0 = out3 + 3 * OUT1;
  float* hbuf1 = hbuf0 + ST;
  float* cbuf  = hbuf1 + ST;
  float* Ct    = cbuf + ST;
  float* Hm    = Ct + OUT1;
  float* Ab    = Hm + (long)B * S * S;

  init_state<<<(6 * B * H + 255) / 256, 256, 0, stream>>>(hQ, cQ, hC, cC, hC2, cC2, hbuf0, cbuf);

  for (int t = 0; t < S; ++t) {
    float* hr = (t & 1) ? hbuf1 : hbuf0;
    float* hw = (t & 1) ? hbuf0 : hbuf1;
    lstm_step<<<dim3(16, 2, 6), 256, 0, stream>>>(
        idxQ, idxC, idxC2, emb,
        Wih_f, Whh_f, bih_f, bhh_f, Wih_b, Whh_b, bih_b, bhh_b,
        hr, hw, cbuf, out3, t);
  }

  for (int p = 0; p < 2; ++p) {
    const float* Q  = out3;
    const float* C0 = out3 + (long)(1 + p) * OUT1;
    gemm_nt<true><<<dim3(8, 256, 1), 256, 0, stream>>>(
        C0, S1W, S1b, Ct, 512, 512, 512, 512, 0, 0, 0);
    gemm_nt<false><<<dim3(2, 2, B), 256, 0, stream>>>(
        Q, Ct, nullptr, Hm, 512, 512, 128, 512,
        (long)S * 512, (long)S * 512, (long)S * S);
    softmax_row<<<B * S, 64, 0, stream>>>(Hm, Ab);
    float* MQ = out + (long)(2 * p) * OUT1;
    gemm_nn<<<dim3(8, 2, B), 256, 0, stream>>>(
        Ab, Q, MQ, 128, 512, 512, 128,
        (long)S * S, (long)S * 512, (long)S * 512);
    softmax_colT<<<B * S, 64, 0, stream>>>(Hm, Ab);
    float* MC = out + (long)(2 * p + 1) * OUT1;
    gemm_nn<<<dim3(8, 2, B), 256, 0, stream>>>(
        Ab, MQ, MC, 128, 512, 512, 128,
        (long)S * S, (long)S * 512, (long)S * 512);
  }
}

// Round 8
// 2240.342 us; speedup vs baseline: 13.7927x; 1.1149x over previous
//
#include <hip/hip_runtime.h>
#include <math.h>

namespace {

constexpr int S = 128;   // seq
constexpr int B = 128;   // batch
constexpr int E = 256;   // embed
constexpr int H = 256;   // hidden

typedef unsigned short u16;
typedef __attribute__((ext_vector_type(8))) short short8v;   // 8 bf16
typedef __attribute__((ext_vector_type(4))) float f32x4;

__device__ __forceinline__ float sigmoidf(float x) { return 1.0f / (1.0f + expf(-x)); }
__device__ __forceinline__ u16 bf16rnd(float x) {
  unsigned u = __float_as_uint(x);
  return (u16)((u + 0x7FFFu + ((u >> 16) & 1u)) >> 16);
}
__device__ __forceinline__ float bf2f(u16 v) { return __uint_as_float(((unsigned)v) << 16); }
__device__ __forceinline__ void split2(float x, u16& h, u16& l) {
  h = bf16rnd(x);
  l = bf16rnd(x - bf2f(h));
}
// gate-interleaved column mapping: col c in [0,1024) -> original W row
__device__ __forceinline__ int gcol_of(int c) {
  return ((c >> 4) & 3) * 256 + ((c & 15) + ((c >> 6) << 4));
}

// ================== split / prep kernels ==================

__global__ void split_pair(const float* __restrict__ src, u16* __restrict__ h,
                           u16* __restrict__ l, long n) {
  long i = (long)blockIdx.x * 256 + threadIdx.x;
  if (i < n) split2(src[i], h[i], l[i]);
}

__global__ void split_w_int(const float* __restrict__ W, u16* __restrict__ h,
                            u16* __restrict__ l) {
  int i = blockIdx.x * 256 + threadIdx.x;   // 1024*256
  int c = i >> 8, k = i & 255;
  split2(W[gcol_of(c) * 256 + k], h[i], l[i]);
}

__global__ void make_bint(const float* __restrict__ bih, const float* __restrict__ bhh,
                          float* __restrict__ bint) {
  int c = blockIdx.x * 256 + threadIdx.x;   // 1024
  int g = gcol_of(c);
  bint[c] = bih[g] + bhh[g];
}

__global__ void init_hc(const float* hQ, const float* cQ, const float* hC, const float* cC,
                        const float* hC2, const float* cC2,
                        u16* hH, u16* hL, float* cst) {
  int i = blockIdx.x * 256 + threadIdx.x;
  if (i >= 6 * B * H) return;
  int z = i / (B * H);
  int rem = i - z * (B * H);
  int input = z >> 1, dir = z & 1;
  const float* hs = input == 0 ? hQ : (input == 1 ? hC : hC2);
  const float* cs = input == 0 ? cQ : (input == 1 ? cC : cC2);
  split2(hs[dir * B * H + rem], hH[i], hL[i]);
  cst[i] = cs[dir * B * H + rem];
}

__global__ void zero_gen(int* gen) {
  if (threadIdx.x < 6) gen[threadIdx.x * 256] = 0;   // 1KB-padded counters
}

// ================== MFMA split-bf16 GEMM kernels ==================
// 256 thr = 4 waves (2x2), block tile 128x128, wave tile 64x64
// = 4x4 MFMA 16x16x32 tiles, K staged in chunks of 32, LDS pitch 40 bf16.
// Fragment maps (gfx950 mfma_f32_16x16x32_bf16):
//   A: row = lane&15, k = (lane>>4)*8 + j    B: col = lane&15, same k
//   D: row = (lane>>4)*4 + reg, col = lane&15   [m89-verified]

#define MFMA_PROLOG                                        \
  const int tid = threadIdx.x;                             \
  const int wave = tid >> 6, lane = tid & 63;              \
  const int wr = wave >> 1, wc = wave & 1;                 \
  const int lrow = lane & 15, lk = lane >> 4;              \
  f32x4 acc[4][4];

#define MFMA_ZERO_ACC                                      \
  _Pragma("unroll") for (int a_ = 0; a_ < 4; ++a_)         \
  _Pragma("unroll") for (int b_ = 0; b_ < 4; ++b_)         \
      acc[a_][b_] = (f32x4){0.f, 0.f, 0.f, 0.f};

#define MFMA_INNER                                                             \
  __syncthreads();                                                             \
  short8v ah[4], al[4];                                                        \
  _Pragma("unroll") for (int mt = 0; mt < 4; ++mt) {                           \
    int r_ = wr * 64 + mt * 16 + lrow;                                         \
    ah[mt] = *(const short8v*)&Ah[r_ * 40 + lk * 8];                           \
    al[mt] = *(const short8v*)&Al[r_ * 40 + lk * 8];                           \
  }                                                                            \
  _Pragma("unroll") for (int nt = 0; nt < 4; ++nt) {                           \
    int c_ = wc * 64 + nt * 16 + lrow;                                         \
    short8v bh = *(const short8v*)&Bh[c_ * 40 + lk * 8];                       \
    short8v bl = *(const short8v*)&Bl[c_ * 40 + lk * 8];                       \
    _Pragma("unroll") for (int mt = 0; mt < 4; ++mt) {                         \
      acc[mt][nt] = __builtin_amdgcn_mfma_f32_16x16x32_bf16(ah[mt], bh, acc[mt][nt], 0, 0, 0); \
      acc[mt][nt] = __builtin_amdgcn_mfma_f32_16x16x32_bf16(ah[mt], bl, acc[mt][nt], 0, 0, 0); \
      acc[mt][nt] = __builtin_amdgcn_mfma_f32_16x16x32_bf16(al[mt], bh, acc[mt][nt], 0, 0, 0); \
    }                                                                          \
  }

// ---- fused persistent LSTM: all 128 steps, x-projection computed in-kernel ----
// grid 128 blocks: z = bx%8 (z>=6 exit; XCD-grouped so each z's 16 blocks share an XCD),
// nb = bx>>3. Block tile M=128 batch x N=64 interleaved gate-cols; 4 waves over m (32 rows).
// LDS: Wih + Whh column slices, hi/lo (4 x 64x264 shorts = 135 KB). Cell state in registers.
// Per step: x-part MFMA (h-independent, hides barrier wait) -> wait h(t-1) -> h-part MFMA
// -> gates -> publish h hi/lo + out3.
__global__ __launch_bounds__(256) void lstm_fused(
    const int* __restrict__ idxQ, const int* __restrict__ idxC, const int* __restrict__ idxC2,
    const u16* __restrict__ embH, const u16* __restrict__ embL,
    const u16* __restrict__ wihHf, const u16* __restrict__ wihLf,
    const u16* __restrict__ wihHb, const u16* __restrict__ wihLb,
    const u16* __restrict__ whhHf, const u16* __restrict__ whhLf,
    const u16* __restrict__ whhHb, const u16* __restrict__ whhLb,
    const float* __restrict__ bintf, const float* __restrict__ bintb,
    u16* __restrict__ hH, u16* __restrict__ hL, const float* __restrict__ cst0,
    u16* __restrict__ out3h, u16* __restrict__ out3l,
    int* __restrict__ gen)
{
  const int bx = blockIdx.x;
  const int z = bx & 7;
  if (z >= 6) return;
  const int nb = bx >> 3;
  const int input = z >> 1, dir = z & 1;
  const int n0c = nb * 64;                 // interleaved col base
  const int tid = threadIdx.x;
  const int wave = tid >> 6, lane = tid & 63;
  const int lrow = lane & 15, lk = lane >> 4;
  const int wr = wave;                     // 4 waves over m: rows wr*32..+31
  const int* idx = input == 0 ? idxQ : (input == 1 ? idxC : idxC2);
  const u16* wiHp = dir ? wihHb : wihHf;
  const u16* wiLp = dir ? wihLb : wihLf;
  const u16* whHp = dir ? whhHb : whhHf;
  const u16* whLp = dir ? whhLb : whhLf;
  const float* bint = dir ? bintb : bintf;

  __shared__ __align__(16) short WiH[64 * 264], WiL[64 * 264];   // pitch 264: benign banking
  __shared__ __align__(16) short WhH[64 * 264], WhL[64 * 264];
  __shared__ int tok[128];

  // one-time W slice loads (amortized over 128 steps)
#pragma unroll
  for (int i = 0; i < 8; ++i) {
    int e = i * 256 + tid;                 // 2048 chunks of 8 bf16 per array
    int c = e >> 5, kc = e & 31;
    long src = (long)(n0c + c) * 256 + kc * 8;
    *(short8v*)&WiH[c * 264 + kc * 8] = *(const short8v*)(wiHp + src);
    *(short8v*)&WiL[c * 264 + kc * 8] = *(const short8v*)(wiLp + src);
    *(short8v*)&WhH[c * 264 + kc * 8] = *(const short8v*)(whHp + src);
    *(short8v*)&WhL[c * 264 + kc * 8] = *(const short8v*)(whLp + src);
  }

  // static per-thread state
  const int u = nb * 16 + lrow;            // unit (0..255); gate == nt
  float bintv[4];
#pragma unroll
  for (int nt = 0; nt < 4; ++nt) bintv[nt] = bint[n0c + nt * 16 + lrow];

  const long HS = (long)6 * B * H;
  const long zb = (long)z * B * H;
  float creg[2][4];                        // cell state: register-resident all 128 steps
#pragma unroll
  for (int mt = 0; mt < 2; ++mt)
#pragma unroll
    for (int rg = 0; rg < 4; ++rg)
      creg[mt][rg] = cst0[zb + (long)(wr * 32 + mt * 16 + lk * 4 + rg) * H + u];

  int* genz = gen + z * 256;               // 1KB padded counter
  u16* o3h = out3h + (long)input * B * S * 512;
  u16* o3l = out3l + (long)input * B * S * 512;

  __syncthreads();                         // W LDS ready

  for (int t = 0; t < S; ++t) {
    const int t_eff = dir ? (S - 1 - t) : t;
    const int par = t & 1;

    if (tid < 128) tok[tid] = idx[t_eff * B + tid];
    __syncthreads();
    const int tv0 = tok[wr * 32 + lrow];
    const int tv1 = tok[wr * 32 + 16 + lrow];

    f32x4 acc[2][4];
#pragma unroll
    for (int mt = 0; mt < 2; ++mt)
#pragma unroll
      for (int nt = 0; nt < 4; ++nt)
        acc[mt][nt] = (f32x4){bintv[nt], bintv[nt], bintv[nt], bintv[nt]};

    // ---- x-part: emb[tok] @ WihI^T (h-independent -> runs before barrier wait) ----
#pragma unroll
    for (int kb = 0; kb < 8; ++kb) {
      short8v ah[2], al[2];
      {
        long e0 = (long)tv0 * 256 + kb * 32 + lk * 8;
        long e1 = (long)tv1 * 256 + kb * 32 + lk * 8;
        ah[0] = *(const short8v*)(embH + e0);
        al[0] = *(const short8v*)(embL + e0);
        ah[1] = *(const short8v*)(embH + e1);
        al[1] = *(const short8v*)(embL + e1);
      }
#pragma unroll
      for (int nt = 0; nt < 4; ++nt) {
        int c = nt * 16 + lrow;
        short8v bh = *(const short8v*)&WiH[c * 264 + kb * 32 + lk * 8];
        short8v bl = *(const short8v*)&WiL[c * 264 + kb * 32 + lk * 8];
#pragma unroll
        for (int mt = 0; mt < 2; ++mt) {
          acc[mt][nt] = __builtin_amdgcn_mfma_f32_16x16x32_bf16(ah[mt], bh, acc[mt][nt], 0, 0, 0);
          acc[mt][nt] = __builtin_amdgcn_mfma_f32_16x16x32_bf16(ah[mt], bl, acc[mt][nt], 0, 0, 0);
          acc[mt][nt] = __builtin_amdgcn_mfma_f32_16x16x32_bf16(al[mt], bh, acc[mt][nt], 0, 0, 0);
        }
      }
    }

    // ---- wait for h(t-1): 16 arrivals per z per step ----
    if (t > 0) {
      if (tid == 0) {
        const int target = 16 * t;
        while (__hip_atomic_load(genz, __ATOMIC_ACQUIRE, __HIP_MEMORY_SCOPE_AGENT) < target) {
          __builtin_amdgcn_s_sleep(2);
        }
      }
      __syncthreads();
    }

    // ---- h-part: h(t-1) @ WhhI^T ----
    const u16* hrH = hH + (long)par * HS + zb;
    const u16* hrL = hL + (long)par * HS + zb;
#pragma unroll
    for (int kb = 0; kb < 8; ++kb) {
      short8v ah[2], al[2];
#pragma unroll
      for (int mt = 0; mt < 2; ++mt) {
        long ho = (long)(wr * 32 + mt * 16 + lrow) * 256 + kb * 32 + lk * 8;
        ah[mt] = *(const short8v*)(hrH + ho);
        al[mt] = *(const short8v*)(hrL + ho);
      }
#pragma unroll
      for (int nt = 0; nt < 4; ++nt) {
        int c = nt * 16 + lrow;
        short8v bh = *(const short8v*)&WhH[c * 264 + kb * 32 + lk * 8];
        short8v bl = *(const short8v*)&WhL[c * 264 + kb * 32 + lk * 8];
#pragma unroll
        for (int mt = 0; mt < 2; ++mt) {
          acc[mt][nt] = __builtin_amdgcn_mfma_f32_16x16x32_bf16(ah[mt], bh, acc[mt][nt], 0, 0, 0);
          acc[mt][nt] = __builtin_amdgcn_mfma_f32_16x16x32_bf16(ah[mt], bl, acc[mt][nt], 0, 0, 0);
          acc[mt][nt] = __builtin_amdgcn_mfma_f32_16x16x32_bf16(al[mt], bh, acc[mt][nt], 0, 0, 0);
        }
      }
    }

    // ---- gates (nt == gate: i,f,g,o), c in registers, publish h ----
    u16* hwH = hH + (long)(par ^ 1) * HS + zb;
    u16* hwL = hL + (long)(par ^ 1) * HS + zb;
#pragma unroll
    for (int mt = 0; mt < 2; ++mt)
#pragma unroll
      for (int rg = 0; rg < 4; ++rg) {
        int row = wr * 32 + mt * 16 + lk * 4 + rg;
        float ig = sigmoidf(acc[mt][0][rg]);
        float fg = sigmoidf(acc[mt][1][rg]);
        float gg = tanhf(acc[mt][2][rg]);
        float og = sigmoidf(acc[mt][3][rg]);
        float cn = fg * creg[mt][rg] + ig * gg;
        creg[mt][rg] = cn;
        float hn = og * tanhf(cn);
        u16 hh, hl;
        split2(hn, hh, hl);
        long ci = (long)row * H + u;
        hwH[ci] = hh;
        hwL[ci] = hl;
        long oi = ((long)row * S + t_eff) * 512 + dir * 256 + u;
        o3h[oi] = hh;
        o3l[oi] = hl;
      }

    // publish: drain stores, block-align, one release add
    asm volatile("s_waitcnt vmcnt(0)" ::: "memory");
    __syncthreads();
    if (tid == 0) {
      __hip_atomic_fetch_add(genz, 1, __ATOMIC_RELEASE, __HIP_MEMORY_SCOPE_AGENT);
    }
  }
}

// ---- Ct = tanh(C0 @ S1W^T + S1b), output split hi/lo ----
// grid (4, 128), block 256. M=16384, N=512, K=512.
__global__ __launch_bounds__(256) void ct_mfma(
    const u16* __restrict__ aH, const u16* __restrict__ aL,
    const u16* __restrict__ s1H, const u16* __restrict__ s1L,
    const float* __restrict__ s1b,
    u16* __restrict__ ctH, u16* __restrict__ ctL)
{
  const int n0 = blockIdx.x * 128, m0 = blockIdx.y * 128;
  __shared__ __align__(16) short Ah[128 * 40], Al[128 * 40], Bh[128 * 40], Bl[128 * 40];
  MFMA_PROLOG
  MFMA_ZERO_ACC

  for (int kb = 0; kb < 512; kb += 32) {
    __syncthreads();
#pragma unroll
    for (int i = 0; i < 2; ++i) {
      int e = i * 256 + tid;
      int r = e >> 2, kg = e & 3;
      long abase = (long)(m0 + r) * 512 + kb + kg * 8;
      *(short8v*)&Ah[r * 40 + kg * 8] = *(const short8v*)(aH + abase);
      *(short8v*)&Al[r * 40 + kg * 8] = *(const short8v*)(aL + abase);
      long bbase = (long)(n0 + r) * 512 + kb + kg * 8;
      *(short8v*)&Bh[r * 40 + kg * 8] = *(const short8v*)(s1H + bbase);
      *(short8v*)&Bl[r * 40 + kg * 8] = *(const short8v*)(s1L + bbase);
    }
    MFMA_INNER
  }

#pragma unroll
  for (int mt = 0; mt < 4; ++mt)
#pragma unroll
    for (int nt = 0; nt < 4; ++nt) {
      int c = n0 + wc * 64 + nt * 16 + lrow;
      float bv = s1b[c];
#pragma unroll
      for (int rg = 0; rg < 4; ++rg) {
        long m = m0 + wr * 64 + mt * 16 + lk * 4 + rg;
        u16 hh, ll;
        split2(tanhf(acc[mt][nt][rg] + bv), hh, ll);
        ctH[m * 512 + c] = hh;
        ctL[m * 512 + c] = ll;
      }
    }
}

// ---- Hm[b] = Q[b] @ Ct[b]^T (fp32 out) ----
__global__ __launch_bounds__(256) void hm_mfma(
    const u16* __restrict__ qH, const u16* __restrict__ qL,
    const u16* __restrict__ ctH, const u16* __restrict__ ctL,
    float* __restrict__ Hm)
{
  const int bb = blockIdx.x;
  const u16* aH = qH + (long)bb * S * 512;
  const u16* aL = qL + (long)bb * S * 512;
  const u16* bH = ctH + (long)bb * S * 512;
  const u16* bL = ctL + (long)bb * S * 512;
  __shared__ __align__(16) short Ah[128 * 40], Al[128 * 40], Bh[128 * 40], Bl[128 * 40];
  MFMA_PROLOG
  MFMA_ZERO_ACC

  for (int kb = 0; kb < 512; kb += 32) {
    __syncthreads();
#pragma unroll
    for (int i = 0; i < 2; ++i) {
      int e = i * 256 + tid;
      int r = e >> 2, kg = e & 3;
      long base = (long)r * 512 + kb + kg * 8;
      *(short8v*)&Ah[r * 40 + kg * 8] = *(const short8v*)(aH + base);
      *(short8v*)&Al[r * 40 + kg * 8] = *(const short8v*)(aL + base);
      *(short8v*)&Bh[r * 40 + kg * 8] = *(const short8v*)(bH + base);
      *(short8v*)&Bl[r * 40 + kg * 8] = *(const short8v*)(bL + base);
    }
    MFMA_INNER
  }

  float* out = Hm + (long)bb * S * S;
#pragma unroll
  for (int mt = 0; mt < 4; ++mt)
#pragma unroll
    for (int nt = 0; nt < 4; ++nt) {
      int c = wc * 64 + nt * 16 + lrow;
#pragma unroll
      for (int rg = 0; rg < 4; ++rg) {
        int m = wr * 64 + mt * 16 + lk * 4 + rg;
        out[(long)m * S + c] = acc[mt][nt][rg];
      }
    }
}

// ---- Qt[b][c][t] planes from o3 planes [b][t][512] (LDS tile transpose) ----
// grid (8 cblk, 2 tblk, 128 b), block 256.
__global__ void transpose_qt(const u16* __restrict__ o3h, const u16* __restrict__ o3l,
                             u16* __restrict__ qth, u16* __restrict__ qtl) {
  const int b = blockIdx.z;
  const int c0 = blockIdx.x * 64, t0 = blockIdx.y * 64;
  __shared__ u16 tile[64][72];
  const int tid = threadIdx.x;
  for (int pl = 0; pl < 2; ++pl) {
    const u16* src = (pl ? o3l : o3h) + (long)b * S * 512;
    u16* dst = (pl ? qtl : qth) + (long)b * 512 * 128;
    __syncthreads();
#pragma unroll
    for (int i = 0; i < 2; ++i) {
      int e = i * 256 + tid;
      int r = e >> 3, sg = e & 7;
      *(short8v*)&tile[r][sg * 8] = *(const short8v*)(src + (long)(t0 + r) * 512 + c0 + sg * 8);
    }
    __syncthreads();
#pragma unroll
    for (int i = 0; i < 2; ++i) {
      int e = i * 256 + tid;
      int c = e >> 3, sg = e & 7;
      short8v v;
#pragma unroll
      for (int j = 0; j < 8; ++j) v[j] = tile[sg * 8 + j][c];
      *(short8v*)(dst + (long)(c0 + c) * 128 + t0 + sg * 8) = v;
    }
  }
}

// ---- pq_mfma: C[b][128][512] = P[b][128x128] @ Bt[b][512x128]^T (K = t dim) ----
// A planes [b][m][k] pitch 128; B planes [b][c][k] pitch 128. grid (4, 1, 128).
// WRITE_T: also emit C^T as bf16 hi/lo planes [b][c][m] (for the MC chain).
template <bool WRITE_T>
__global__ __launch_bounds__(256) void pq_mfma(
    const u16* __restrict__ pH, const u16* __restrict__ pL,
    const u16* __restrict__ btH, const u16* __restrict__ btL,
    float* __restrict__ Cout, u16* __restrict__ tH, u16* __restrict__ tL)
{
  const int bb = blockIdx.z, n0 = blockIdx.x * 128;
  const u16* aHp = pH + (long)bb * 128 * 128;
  const u16* aLp = pL + (long)bb * 128 * 128;
  const u16* bHp = btH + ((long)bb * 512 + n0) * 128;
  const u16* bLp = btL + ((long)bb * 512 + n0) * 128;
  __shared__ __align__(16) short Ah[128 * 40], Al[128 * 40], Bh[128 * 40], Bl[128 * 40];
  MFMA_PROLOG
  MFMA_ZERO_ACC

  for (int kb = 0; kb < 128; kb += 32) {
    __syncthreads();
#pragma unroll
    for (int i = 0; i < 2; ++i) {
      int e = i * 256 + tid;
      int r = e >> 2, kg = e & 3;
      long base = (long)r * 128 + kb + kg * 8;
      *(short8v*)&Ah[r * 40 + kg * 8] = *(const short8v*)(aHp + base);
      *(short8v*)&Al[r * 40 + kg * 8] = *(const short8v*)(aLp + base);
      *(short8v*)&Bh[r * 40 + kg * 8] = *(const short8v*)(bHp + base);
      *(short8v*)&Bl[r * 40 + kg * 8] = *(const short8v*)(bLp + base);
    }
    MFMA_INNER
  }

  float* co = Cout + (long)bb * 128 * 512;
#pragma unroll
  for (int mt = 0; mt < 4; ++mt)
#pragma unroll
    for (int nt = 0; nt < 4; ++nt) {
      int c = n0 + wc * 64 + nt * 16 + lrow;
#pragma unroll
      for (int rg = 0; rg < 4; ++rg) {
        int m = wr * 64 + mt * 16 + lk * 4 + rg;
        float v = acc[mt][nt][rg];
        co[(long)m * 512 + c] = v;
        if (WRITE_T) {
          u16 hh, ll;
          split2(v, hh, ll);
          tH[((long)bb * 512 + c) * 128 + m] = hh;
          tL[((long)bb * 512 + c) * 128 + m] = ll;
        }
      }
    }
}

// ---------------- softmaxes ----------------
__global__ void softmax_row_bf(const float* __restrict__ Hm, u16* __restrict__ ph,
                               u16* __restrict__ pl) {
  const int row = blockIdx.x;
  const float* p = Hm + (long)row * S;
  const int l = threadIdx.x;
  float v0 = p[l], v1 = p[l + 64];
  float m = fmaxf(v0, v1);
#pragma unroll
  for (int o = 32; o > 0; o >>= 1) m = fmaxf(m, __shfl_xor(m, o));
  float e0 = expf(v0 - m), e1 = expf(v1 - m);
  float s = e0 + e1;
#pragma unroll
  for (int o = 32; o > 0; o >>= 1) s += __shfl_xor(s, o);
  float inv = 1.0f / s;
  u16 hh, ll;
  split2(e0 * inv, hh, ll);
  ph[(long)row * S + l] = hh; pl[(long)row * S + l] = ll;
  split2(e1 * inv, hh, ll);
  ph[(long)row * S + l + 64] = hh; pl[(long)row * S + l + 64] = ll;
}

__global__ void softmax_colT_bf(const float* __restrict__ Hm, u16* __restrict__ ph,
                                u16* __restrict__ pl) {
  const int b = blockIdx.x >> 7;
  const int col = blockIdx.x & 127;
  const float* p = Hm + (long)b * S * S + col;
  const int l = threadIdx.x;
  float v0 = p[(long)l * S], v1 = p[(long)(l + 64) * S];
  float m = fmaxf(v0, v1);
#pragma unroll
  for (int o = 32; o > 0; o >>= 1) m = fmaxf(m, __shfl_xor(m, o));
  float e0 = expf(v0 - m), e1 = expf(v1 - m);
  float s = e0 + e1;
#pragma unroll
  for (int o = 32; o > 0; o >>= 1) s += __shfl_xor(s, o);
  float inv = 1.0f / s;
  long q = ((long)b * S + col) * S;
  u16 hh, ll;
  split2(e0 * inv, hh, ll);
  ph[q + l] = hh; pl[q + l] = ll;
  split2(e1 * inv, hh, ll);
  ph[q + l + 64] = hh; pl[q + l + 64] = ll;
}

// fp32 softmaxes for the fallback path
__global__ void softmax_row(const float* __restrict__ Hm, float* __restrict__ A) {
  const int row = blockIdx.x;
  const float* p = Hm + (long)row * S;
  const int l = threadIdx.x;
  float v0 = p[l], v1 = p[l + 64];
  float m = fmaxf(v0, v1);
#pragma unroll
  for (int o = 32; o > 0; o >>= 1) m = fmaxf(m, __shfl_xor(m, o));
  float e0 = expf(v0 - m), e1 = expf(v1 - m);
  float s = e0 + e1;
#pragma unroll
  for (int o = 32; o > 0; o >>= 1) s += __shfl_xor(s, o);
  float inv = 1.0f / s;
  float* q = A + (long)row * S;
  q[l] = e0 * inv; q[l + 64] = e1 * inv;
}

__global__ void softmax_colT(const float* __restrict__ Hm, float* __restrict__ A) {
  const int b = blockIdx.x >> 7;
  const int col = blockIdx.x & 127;
  const float* p = Hm + (long)b * S * S + col;
  const int l = threadIdx.x;
  float v0 = p[(long)l * S], v1 = p[(long)(l + 64) * S];
  float m = fmaxf(v0, v1);
#pragma unroll
  for (int o = 32; o > 0; o >>= 1) m = fmaxf(m, __shfl_xor(m, o));
  float e0 = expf(v0 - m), e1 = expf(v1 - m);
  float s = e0 + e1;
#pragma unroll
  for (int o = 32; o > 0; o >>= 1) s += __shfl_xor(s, o);
  float inv = 1.0f / s;
  float* q = A + ((long)b * S + col) * S;
  q[l] = e0 * inv; q[l + 64] = e1 * inv;
}

// ================== FALLBACK PATH (round-1, verified) ==================

__global__ void init_state(const float* hQ, const float* cQ,
                           const float* hC, const float* cC,
                           const float* hC2, const float* cC2,
                           float* h0, float* c0) {
  int i = blockIdx.x * 256 + threadIdx.x;
  if (i >= 6 * B * H) return;
  int z = i / (B * H);
  int rem = i - z * (B * H);
  int input = z >> 1, dir = z & 1;
  const float* hs = input == 0 ? hQ : (input == 1 ? hC : hC2);
  const float* cs = input == 0 ? cQ : (input == 1 ? cC : cC2);
  h0[i] = hs[dir * B * H + rem];
  c0[i] = cs[dir * B * H + rem];
}

__global__ __launch_bounds__(256) void lstm_step(
    const int* __restrict__ idxQ, const int* __restrict__ idxC, const int* __restrict__ idxC2,
    const float* __restrict__ emb,
    const float* __restrict__ Wih_f, const float* __restrict__ Whh_f,
    const float* __restrict__ bih_f, const float* __restrict__ bhh_f,
    const float* __restrict__ Wih_b, const float* __restrict__ Whh_b,
    const float* __restrict__ bih_b, const float* __restrict__ bhh_b,
    const float* __restrict__ hread, float* __restrict__ hwrite,
    float* __restrict__ cstate, float* __restrict__ out3, int t)
{
  const int z = blockIdx.z;
  const int input = z >> 1, dir = z & 1;
  const int u0 = blockIdx.x * 16;
  const int b0 = blockIdx.y * 64;
  const int t_eff = dir ? (S - 1 - t) : t;
  const int* idx = input == 0 ? idxQ : (input == 1 ? idxC : idxC2);
  const float* Wih = dir ? Wih_b : Wih_f;
  const float* Whh = dir ? Whh_b : Whh_f;
  const float* bih = dir ? bih_b : bih_f;
  const float* bhh = dir ? bhh_b : bhh_f;

  __shared__ float Alds[64][68];
  __shared__ float Wl[64][68];
  __shared__ int tok[64];

  const int tid = threadIdx.x;
  if (tid < 64) tok[tid] = idx[t_eff * B + b0 + tid];

  const int uu = tid & 15;
  const int rg = tid >> 4;
  const int u = u0 + uu;

  float acc[4][4];
#pragma unroll
  for (int ri = 0; ri < 4; ++ri)
#pragma unroll
    for (int g = 0; g < 4; ++g)
      acc[ri][g] = bih[g * 256 + u] + bhh[g * 256 + u];

  for (int kc = 0; kc < 8; ++kc) {
    __syncthreads();
    if (kc < 4) {
      const int kb = kc * 64;
#pragma unroll
      for (int i = 0; i < 16; ++i) {
        int e = i * 256 + tid;
        int kk = e & 63, r = e >> 6;
        Alds[r][kk] = emb[(long)tok[r] * E + kb + kk];
      }
    } else {
      const int kb = (kc - 4) * 64;
      const float* hs = hread + ((long)z * B + b0) * H + kb;
#pragma unroll
      for (int i = 0; i < 16; ++i) {
        int e = i * 256 + tid;
        int kk = e & 63, r = e >> 6;
        Alds[r][kk] = hs[r * H + kk];
      }
    }
    {
      const float* Wsrc = (kc < 4) ? Wih : Whh;
      const int kb = (kc & 3) * 64;
#pragma unroll
      for (int i = 0; i < 16; ++i) {
        int e = i * 256 + tid;
        int kk = e & 63, c = e >> 6;
        int gcol = (c >> 4) * 256 + u0 + (c & 15);
        Wl[c][kk] = Wsrc[(long)gcol * H + kb + kk];
      }
    }
    __syncthreads();
#pragma unroll
    for (int k4 = 0; k4 < 64; k4 += 4) {
      float4 a[4], w[4];
#pragma unroll
      for (int ri = 0; ri < 4; ++ri) a[ri] = *(const float4*)&Alds[rg * 4 + ri][k4];
#pragma unroll
      for (int g = 0; g < 4; ++g) w[g] = *(const float4*)&Wl[g * 16 + uu][k4];
#pragma unroll
      for (int ri = 0; ri < 4; ++ri)
#pragma unroll
        for (int g = 0; g < 4; ++g)
          acc[ri][g] += a[ri].x * w[g].x + a[ri].y * w[g].y
                      + a[ri].z * w[g].z + a[ri].w * w[g].w;
    }
  }

  float* cs = cstate + (long)z * B * H;
  float* hw = hwrite + (long)z * B * H;
  float* op = out3 + (long)input * B * S * 2 * H;
#pragma unroll
  for (int ri = 0; ri < 4; ++ri) {
    int b = b0 + rg * 4 + ri;
    float ig = sigmoidf(acc[ri][0]);
    float fg = sigmoidf(acc[ri][1]);
    float gg = tanhf(acc[ri][2]);
    float og = sigmoidf(acc[ri][3]);
    float cn = fg * cs[b * H + u] + ig * gg;
    float hn = og * tanhf(cn);
    cs[b * H + u] = cn;
    hw[b * H + u] = hn;
    op[((long)b * S + t_eff) * (2 * H) + dir * H + u] = hn;
  }
}

template <bool TANH>
__global__ __launch_bounds__(256) void gemm_nt(
    const float* __restrict__ A, const float* __restrict__ B_,
    const float* __restrict__ bias, float* __restrict__ C,
    int lda, int ldb, int ldc, int K, long sA, long sB, long sC)
{
  A += blockIdx.z * sA; B_ += blockIdx.z * sB; C += blockIdx.z * sC;
  const int n0 = blockIdx.x * 64, m0 = blockIdx.y * 64;
  __shared__ float Alds[64][68], Blds[64][68];
  const int tid = threadIdx.x, uu = tid & 15, rg = tid >> 4;
  float acc[4][4] = {};
  for (int kb = 0; kb < K; kb += 64) {
    __syncthreads();
#pragma unroll
    for (int i = 0; i < 16; ++i) {
      int e = i * 256 + tid;
      int kk = e & 63, r = e >> 6;
      Alds[r][kk] = A[(long)(m0 + r) * lda + kb + kk];
      Blds[r][kk] = B_[(long)(n0 + r) * ldb + kb + kk];
    }
    __syncthreads();
#pragma unroll
    for (int k4 = 0; k4 < 64; k4 += 4) {
      float4 a[4], w[4];
#pragma unroll
      for (int ri = 0; ri < 4; ++ri) a[ri] = *(const float4*)&Alds[rg * 4 + ri][k4];
#pragma unroll
      for (int ci = 0; ci < 4; ++ci) w[ci] = *(const float4*)&Blds[ci * 16 + uu][k4];
#pragma unroll
      for (int ri = 0; ri < 4; ++ri)
#pragma unroll
        for (int ci = 0; ci < 4; ++ci)
          acc[ri][ci] += a[ri].x * w[ci].x + a[ri].y * w[ci].y
                       + a[ri].z * w[ci].z + a[ri].w * w[ci].w;
    }
  }
#pragma unroll
  for (int ri = 0; ri < 4; ++ri) {
    int m = m0 + rg * 4 + ri;
#pragma unroll
    for (int ci = 0; ci < 4; ++ci) {
      int n = n0 + ci * 16 + uu;
      float v = acc[ri][ci];
      if (bias) v += bias[n];
      if (TANH) v = tanhf(v);
      C[(long)m * ldc + n] = v;
    }
  }
}

__global__ __launch_bounds__(256) void gemm_nn(
    const float* __restrict__ A, const float* __restrict__ B_,
    float* __restrict__ C,
    int lda, int ldb, int ldc, int K, long sA, long sB, long sC)
{
  A += blockIdx.z * sA; B_ += blockIdx.z * sB; C += blockIdx.z * sC;
  const int n0 = blockIdx.x * 64, m0 = blockIdx.y * 64;
  __shared__ float Alds[64][68];
  __shared__ float Blds[64][68];
  const int tid = threadIdx.x, uu = tid & 15, rg = tid >> 4;
  float acc[4][4] = {};
  for (int kb = 0; kb < K; kb += 64) {
    __syncthreads();
#pragma unroll
    for (int i = 0; i < 16; ++i) {
      int e = i * 256 + tid;
      int kk = e & 63, r = e >> 6;
      Alds[r][kk] = A[(long)(m0 + r) * lda + kb + kk];
      Blds[r][kk] = B_[(long)(kb + r) * ldb + n0 + kk];
    }
    __syncthreads();
#pragma unroll
    for (int kk = 0; kk < 64; ++kk) {
      float4 w = *(const float4*)&Blds[kk][uu * 4];
      float a0 = Alds[rg * 4 + 0][kk], a1 = Alds[rg * 4 + 1][kk];
      float a2 = Alds[rg * 4 + 2][kk], a3 = Alds[rg * 4 + 3][kk];
      acc[0][0] += a0 * w.x; acc[0][1] += a0 * w.y; acc[0][2] += a0 * w.z; acc[0][3] += a0 * w.w;
      acc[1][0] += a1 * w.x; acc[1][1] += a1 * w.y; acc[1][2] += a1 * w.z; acc[1][3] += a1 * w.w;
      acc[2][0] += a2 * w.x; acc[2][1] += a2 * w.y; acc[2][2] += a2 * w.z; acc[2][3] += a2 * w.w;
      acc[3][0] += a3 * w.x; acc[3][1] += a3 * w.y; acc[3][2] += a3 * w.z; acc[3][3] += a3 * w.w;
    }
  }
#pragma unroll
  for (int ri = 0; ri < 4; ++ri) {
    int m = m0 + rg * 4 + ri;
    float4 v = make_float4(acc[ri][0], acc[ri][1], acc[ri][2], acc[ri][3]);
    *(float4*)&C[(long)m * ldc + n0 + uu * 4] = v;
  }
}

}  // namespace

extern "C" void kernel_launch(void* const* d_in, const int* in_sizes, int n_in,
                              void* d_out, int out_size, void* d_ws, size_t ws_size,
                              hipStream_t stream) {
  const int* idxQ    = (const int*)d_in[1];
  const int* idxC    = (const int*)d_in[2];
  const int* idxC2   = (const int*)d_in[3];
  const float* hQ    = (const float*)d_in[4];
  const float* cQ    = (const float*)d_in[5];
  const float* hC    = (const float*)d_in[6];
  const float* cC    = (const float*)d_in[7];
  const float* hC2   = (const float*)d_in[8];
  const float* cC2   = (const float*)d_in[9];
  const float* emb   = (const float*)d_in[10];
  const float* Wih_f = (const float*)d_in[11];
  const float* Whh_f = (const float*)d_in[12];
  const float* bih_f = (const float*)d_in[13];
  const float* bhh_f = (const float*)d_in[14];
  const float* Wih_b = (const float*)d_in[15];
  const float* Whh_b = (const float*)d_in[16];
  const float* bih_b = (const float*)d_in[17];
  const float* bhh_b = (const float*)d_in[18];
  const float* S1W   = (const float*)d_in[19];
  const float* S1b   = (const float*)d_in[20];
  float* out = (float*)d_out;

  const long V = 50000;
  const long OUT1 = (long)B * S * 2 * H;   // 8,388,608 floats per input

  // -------- fast-path workspace layout (bytes) --------
  size_t off = 0;
  auto alloc = [&](size_t bytes) { size_t o = off; off += (bytes + 255) & ~(size_t)255; return o; };
  const size_t o_o3h  = alloc((size_t)3 * B * S * 512 * 2);
  const size_t o_o3l  = alloc((size_t)3 * B * S * 512 * 2);
  const size_t o_embH = alloc((size_t)V * E * 2);
  const size_t o_embL = alloc((size_t)V * E * 2);
  const size_t o_wihHf = alloc(1024 * 256 * 2), o_wihLf = alloc(1024 * 256 * 2);
  const size_t o_wihHb = alloc(1024 * 256 * 2), o_wihLb = alloc(1024 * 256 * 2);
  const size_t o_whhHf = alloc(1024 * 256 * 2), o_whhLf = alloc(1024 * 256 * 2);
  const size_t o_whhHb = alloc(1024 * 256 * 2), o_whhLb = alloc(1024 * 256 * 2);
  const size_t o_s1H  = alloc(512 * 512 * 2), o_s1L = alloc(512 * 512 * 2);
  const size_t o_bintf = alloc(1024 * 4), o_bintb = alloc(1024 * 4);
  const size_t o_hH   = alloc((size_t)2 * 6 * B * H * 2);
  const size_t o_hL   = alloc((size_t)2 * 6 * B * H * 2);
  const size_t o_cst  = alloc((size_t)6 * B * H * 4);
  const size_t o_gen  = alloc(6 * 256 * 4);
  const size_t o_ctH  = alloc((size_t)B * S * 512 * 2);
  const size_t o_ctL  = alloc((size_t)B * S * 512 * 2);
  const size_t o_Hm   = alloc((size_t)B * S * S * 4);
  const size_t o_Ph   = alloc((size_t)B * S * S * 2);
  const size_t o_Pl   = alloc((size_t)B * S * S * 2);
  const size_t o_QtH  = alloc((size_t)B * 512 * 128 * 2);
  const size_t o_QtL  = alloc((size_t)B * 512 * 128 * 2);
  const size_t o_MQtH = alloc((size_t)B * 512 * 128 * 2);
  const size_t o_MQtL = alloc((size_t)B * 512 * 128 * 2);
  const size_t need_fast = off;   // ~260 MB

  if (ws_size >= need_fast) {
    char* base = (char*)d_ws;
    u16* o3h = (u16*)(base + o_o3h);
    u16* o3l = (u16*)(base + o_o3l);
    u16* embH = (u16*)(base + o_embH);
    u16* embL = (u16*)(base + o_embL);
    u16* wihHf = (u16*)(base + o_wihHf); u16* wihLf = (u16*)(base + o_wihLf);
    u16* wihHb = (u16*)(base + o_wihHb); u16* wihLb = (u16*)(base + o_wihLb);
    u16* whhHf = (u16*)(base + o_whhHf); u16* whhLf = (u16*)(base + o_whhLf);
    u16* whhHb = (u16*)(base + o_whhHb); u16* whhLb = (u16*)(base + o_whhLb);
    u16* s1H = (u16*)(base + o_s1H); u16* s1L = (u16*)(base + o_s1L);
    float* bintf = (float*)(base + o_bintf);
    float* bintb = (float*)(base + o_bintb);
    u16* hH = (u16*)(base + o_hH);
    u16* hL = (u16*)(base + o_hL);
    float* cst = (float*)(base + o_cst);
    int* gen = (int*)(base + o_gen);
    u16* ctH = (u16*)(base + o_ctH);
    u16* ctL = (u16*)(base + o_ctL);
    float* Hm = (float*)(base + o_Hm);
    u16* Ph = (u16*)(base + o_Ph);
    u16* Pl = (u16*)(base + o_Pl);
    u16* QtH = (u16*)(base + o_QtH);
    u16* QtL = (u16*)(base + o_QtL);
    u16* MQtH = (u16*)(base + o_MQtH);
    u16* MQtL = (u16*)(base + o_MQtL);

    // ---- prep ----
    split_pair<<<(int)((V * E + 255) / 256), 256, 0, stream>>>(emb, embH, embL, V * E);
    split_w_int<<<1024, 256, 0, stream>>>(Wih_f, wihHf, wihLf);
    split_w_int<<<1024, 256, 0, stream>>>(Wih_b, wihHb, wihLb);
    split_w_int<<<1024, 256, 0, stream>>>(Whh_f, whhHf, whhLf);
    split_w_int<<<1024, 256, 0, stream>>>(Whh_b, whhHb, whhLb);
    split_pair<<<1024, 256, 0, stream>>>(S1W, s1H, s1L, 512 * 512);
    make_bint<<<4, 256, 0, stream>>>(bih_f, bhh_f, bintf);
    make_bint<<<4, 256, 0, stream>>>(bih_b, bhh_b, bintb);
    init_hc<<<(6 * B * H + 255) / 256, 256, 0, stream>>>(hQ, cQ, hC, cC, hC2, cC2, hH, hL, cst);
    zero_gen<<<1, 64, 0, stream>>>(gen);

    // ---- LSTM: single cooperative launch, all 128 steps, fused x-projection ----
    {
      const int* a0 = idxQ; const int* a1 = idxC; const int* a2 = idxC2;
      const u16* a3 = embH; const u16* a4 = embL;
      const u16* a5 = wihHf; const u16* a6 = wihLf;
      const u16* a7 = wihHb; const u16* a8 = wihLb;
      const u16* a9 = whhHf; const u16* a10 = whhLf;
      const u16* a11 = whhHb; const u16* a12 = whhLb;
      const float* a13 = bintf; const float* a14 = bintb;
      u16* a15 = hH; u16* a16 = hL; const float* a17 = cst;
      u16* a18 = o3h; u16* a19 = o3l; int* a20 = gen;
      void* kargs[] = {(void*)&a0, (void*)&a1, (void*)&a2, (void*)&a3, (void*)&a4,
                       (void*)&a5, (void*)&a6, (void*)&a7, (void*)&a8, (void*)&a9,
                       (void*)&a10, (void*)&a11, (void*)&a12, (void*)&a13, (void*)&a14,
                       (void*)&a15, (void*)&a16, (void*)&a17, (void*)&a18, (void*)&a19,
                       (void*)&a20};
      hipLaunchCooperativeKernel((const void*)lstm_fused, dim3(128), dim3(256),
                                 kargs, 0, stream);
    }

    // ---- attention x2 ----
    transpose_qt<<<dim3(8, 2, 128), 256, 0, stream>>>(o3h, o3l, QtH, QtL);
    for (int p = 0; p < 2; ++p) {
      const u16* aH = o3h + (size_t)(1 + p) * B * S * 512;
      const u16* aL = o3l + (size_t)(1 + p) * B * S * 512;
      ct_mfma<<<dim3(4, 128), 256, 0, stream>>>(aH, aL, s1H, s1L, S1b, ctH, ctL);
      hm_mfma<<<128, 256, 0, stream>>>(o3h, o3l, ctH, ctL, Hm);
      softmax_row_bf<<<B * S, 64, 0, stream>>>(Hm, Ph, Pl);
      float* MQ = out + (long)(2 * p) * OUT1;
      pq_mfma<true><<<dim3(4, 1, 128), 256, 0, stream>>>(
          Ph, Pl, QtH, QtL, MQ, MQtH, MQtL);
      softmax_colT_bf<<<B * S, 64, 0, stream>>>(Hm, Ph, Pl);
      float* MC = out + (long)(2 * p + 1) * OUT1;
      pq_mfma<false><<<dim3(4, 1, 128), 256, 0, stream>>>(
          Ph, Pl, MQtH, MQtL, MC, nullptr, nullptr);
    }
    return;
  }

  // -------- fallback path: round-1 verified --------
  const long ST = (long)6 * B * H;
  float* ws    = (float*)d_ws;
  float* out3  = ws;
  float* hbuf0 = out3 + 3 * OUT1;
  float* hbuf1 = hbuf0 + ST;
  float* cbuf  = hbuf1 + ST;
  float* Ct    = cbuf + ST;
  float* Hm    = Ct + OUT1;
  float* Ab    = Hm + (long)B * S * S;

  init_state<<<(6 * B * H + 255) / 256, 256, 0, stream>>>(hQ, cQ, hC, cC, hC2, cC2, hbuf0, cbuf);

  for (int t = 0; t < S; ++t) {
    float* hr = (t & 1) ? hbuf1 : hbuf0;
    float* hw = (t & 1) ? hbuf0 : hbuf1;
    lstm_step<<<dim3(16, 2, 6), 256, 0, stream>>>(
        idxQ, idxC, idxC2, emb,
        Wih_f, Whh_f, bih_f, bhh_f, Wih_b, Whh_b, bih_b, bhh_b,
        hr, hw, cbuf, out3, t);
  }

  for (int p = 0; p < 2; ++p) {
    const float* Q  = out3;
    const float* C0 = out3 + (long)(1 + p) * OUT1;
    gemm_nt<true><<<dim3(8, 256, 1), 256, 0, stream>>>(
        C0, S1W, S1b, Ct, 512, 512, 512, 512, 0, 0, 0);
    gemm_nt<false><<<dim3(2, 2, B), 256, 0, stream>>>(
        Q, Ct, nullptr, Hm, 512, 512, 128, 512,
        (long)S * 512, (long)S * 512, (long)S * S);
    softmax_row<<<B * S, 64, 0, stream>>>(Hm, Ab);
    float* MQ = out + (long)(2 * p) * OUT1;
    gemm_nn<<<dim3(8, 2, B), 256, 0, stream>>>(
        Ab, Q, MQ, 128, 512, 512, 128,
        (long)S * S, (long)S * 512, (long)S * 512);
    softmax_colT<<<B * S, 64, 0, stream>>>(Hm, Ab);
    float* MC = out + (long)(2 * p + 1) * OUT1;
    gemm_nn<<<dim3(8, 2, B), 256, 0, stream>>>(
        Ab, MQ, MC, 128, 512, 512, 128,
        (long)S * S, (long)S * 512, (long)S * 512);
  }
}